// Round 3
// baseline (1558.318 us; speedup 1.0000x reference)
//
#include <hip/hip_runtime.h>
#include <math.h>

#define B_ 64
#define T_ 256
#define F_ 64
#define H_ 64
#define NROW (B_ * F_) /* 4096 */

__device__ __forceinline__ float bcastf(float v, int k) {
  return __int_as_float(__builtin_amdgcn_readlane(__float_as_int(v), k));
}

__device__ __forceinline__ float sigm(float x) {
  return 1.0f / (1.0f + __expf(-x));
}

__device__ __forceinline__ float tanh_f(float x) {
  float ax = fabsf(x);
  float e = __expf(-2.0f * ax);
  float r = (1.0f - e) / (1.0f + e);
  return copysignf(r, x);
}

// Pin a float4's components into VGPRs: opaque to rematerialization.
#define PIN4(v) asm volatile("" : "+v"((v).x), "+v"((v).y), "+v"((v).z), "+v"((v).w))

// One wave per (direction, row); 64-thread blocks. Lane j owns GRU unit j.
// w_hh rows {j, 64+j, 128+j} pinned in VGPRs (192 regs) via empty-asm so the
// compiler cannot re-load them inside the t-loop.
__global__ void __launch_bounds__(64, 2)
gru_kernel(const float* __restrict__ Xf, const float* __restrict__ Mf, const float* __restrict__ Df,
           const float* __restrict__ Xb, const float* __restrict__ Mb, const float* __restrict__ Db,
           const float* __restrict__ wih_f, const float* __restrict__ whh_f,
           const float* __restrict__ bih_f, const float* __restrict__ bhh_f,
           const float* __restrict__ wih_b, const float* __restrict__ whh_b,
           const float* __restrict__ bih_b, const float* __restrict__ bhh_b,
           const float* __restrict__ Wproj,
           float* __restrict__ est_f, float* __restrict__ est_b)
{
  const int lane = threadIdx.x;                 // 0..63
  // XCD-chunked bijective swizzle: 8192 blocks, 8 XCDs -> each XCD gets a
  // contiguous 1024-row chunk (same-b rows share L2 lines).
  const int rho  = (blockIdx.x & 7) * 1024 + (blockIdx.x >> 3);  // 0..8191
  const int dir  = rho >> 12;                   // 0 fwd, 1 bwd
  const int n    = rho & (NROW - 1);
  const int b    = n >> 6;
  const int f    = n & 63;

  const float* X   = dir ? Xb    : Xf;
  const float* M   = dir ? Mb    : Mf;
  const float* D   = dir ? Db    : Df;
  const float* wih = dir ? wih_b : wih_f;
  const float* whh = dir ? whh_b : whh_f;
  const float* bih = dir ? bih_b : bih_f;
  const float* bhh = dir ? bhh_b : bhh_f;
  float* est       = dir ? est_b : est_f;

  // per-lane weight rows (unit j = lane), pinned into VGPRs
  float4 wr4[16], wz4[16], wn4[16];
#pragma unroll
  for (int k4 = 0; k4 < 16; ++k4) {
    wr4[k4] = *(const float4*)&whh[(0 * H_ + lane) * H_ + 4 * k4];
    wz4[k4] = *(const float4*)&whh[(1 * H_ + lane) * H_ + 4 * k4];
    wn4[k4] = *(const float4*)&whh[(2 * H_ + lane) * H_ + 4 * k4];
    PIN4(wr4[k4]); PIN4(wz4[k4]); PIN4(wn4[k4]);
  }
  const float wir0 = wih[(0 * H_ + lane) * 3 + 0];
  const float wir1 = wih[(0 * H_ + lane) * 3 + 1];
  const float wir2 = wih[(0 * H_ + lane) * 3 + 2];
  const float wiz0 = wih[(1 * H_ + lane) * 3 + 0];
  const float wiz1 = wih[(1 * H_ + lane) * 3 + 1];
  const float wiz2 = wih[(1 * H_ + lane) * 3 + 2];
  const float win0 = wih[(2 * H_ + lane) * 3 + 0];
  const float win1 = wih[(2 * H_ + lane) * 3 + 1];
  const float win2 = wih[(2 * H_ + lane) * 3 + 2];
  const float br  = bih[0 * H_ + lane] + bhh[0 * H_ + lane];
  const float bz  = bih[1 * H_ + lane] + bhh[1 * H_ + lane];
  const float bin = bih[2 * H_ + lane];            // n = tanh(i_n + r*gh_n)
  const float bhn = bhh[2 * H_ + lane];
  const float Wp  = Wproj[dir * H_ + lane];

  float h = 0.0f;
  const size_t base = (size_t)b * T_ * F_ + f;
  float xv = X[base], mv = M[base], dv = D[base];

  for (int t = 0; t < T_; ++t) {
    // branchless prefetch of next step's inputs (clamped index)
    size_t nidx = base + (size_t)((t + 1 < T_) ? (t + 1) : t) * F_;
    float xn = X[nidx], mn = M[nidx], dn = D[nidx];

    float ar = fmaf(xv, wir0, fmaf(mv, wir1, fmaf(dv, wir2, br)));
    float az = fmaf(xv, wiz0, fmaf(mv, wiz1, fmaf(dv, wiz2, bz)));
    float an = fmaf(xv, win0, fmaf(mv, win1, fmaf(dv, win2, bin)));
    float ah = bhn;
#pragma unroll
    for (int k4 = 0; k4 < 16; ++k4) {
      const float4 wrv = wr4[k4];
      const float4 wzv = wz4[k4];
      const float4 wnv = wn4[k4];
      float h0 = bcastf(h, 4 * k4 + 0);
      float h1 = bcastf(h, 4 * k4 + 1);
      float h2 = bcastf(h, 4 * k4 + 2);
      float h3 = bcastf(h, 4 * k4 + 3);
      ar = fmaf(h0, wrv.x, ar); az = fmaf(h0, wzv.x, az); ah = fmaf(h0, wnv.x, ah);
      ar = fmaf(h1, wrv.y, ar); az = fmaf(h1, wzv.y, az); ah = fmaf(h1, wnv.y, ah);
      ar = fmaf(h2, wrv.z, ar); az = fmaf(h2, wzv.z, az); ah = fmaf(h2, wnv.z, ah);
      ar = fmaf(h3, wrv.w, ar); az = fmaf(h3, wzv.w, az); ah = fmaf(h3, wnv.w, ah);
    }
    float r  = sigm(ar);
    float z  = sigm(az);
    float nn = tanh_f(fmaf(r, ah, an));
    h = fmaf(z, h - nn, nn);               // (1-z)*n + z*h

    float p = h * Wp;                      // est partial; reduce over 64 lanes
#pragma unroll
    for (int off = 32; off; off >>= 1) p += __shfl_xor(p, off, 64);
    if (lane == 0) {
      int tt = dir ? (T_ - 1 - t) : t;     // backward: un-flip
      est[(size_t)tt * NROW + n] = p;
    }
    xv = xn; mv = mn; dv = dn;
  }
}

#define FS 65  /* padded LDS stride: 2 lanes/bank = free */

// One wave per (b,t) sample; lane = output feature o.
__global__ void __launch_bounds__(256, 2)
fcn_kernel(const float* __restrict__ X, const float* __restrict__ M,
           const float* __restrict__ U, const float* __restrict__ V1, const float* __restrict__ V2,
           const float* __restrict__ beta, const float* __restrict__ Wfin, const float* __restrict__ bfin,
           const float* __restrict__ bproj,
           const float* __restrict__ est_f, const float* __restrict__ est_b,
           float* __restrict__ out, float* __restrict__ acc)
{
  __shared__ float sU[64 * FS], sV1[64 * FS], sV2[64 * FS];
  __shared__ float sbeta[64], sbfin[64];
  __shared__ float red[3][4];
  const int tid  = threadIdx.x;
  const int lane = tid & 63;
  const int wid  = tid >> 6;

  for (int idx = tid; idx < 64 * 64; idx += 256) {
    int o = idx >> 6, i = idx & 63;
    sU [o * FS + i] = U [idx];
    sV1[o * FS + i] = V1[idx];
    sV2[o * FS + i] = V2[idx];
  }
  if (tid < 64) { sbeta[tid] = beta[tid]; sbfin[tid] = bfin[tid]; }
  __syncthreads();

  float4 wfr4[16];                         // W_fin row o in VGPRs
#pragma unroll
  for (int k4 = 0; k4 < 16; ++k4) {
    wfr4[k4] = *(const float4*)&Wfin[lane * 64 + 4 * k4];
    PIN4(wfr4[k4]);
  }

  const float bp = bproj[0];
  float se1 = 0.f, se2 = 0.f, sm = 0.f;

  const int SPB = 16;                      // samples per block
  for (int si = 0; si < SPB / 4; ++si) {
    int s  = blockIdx.x * SPB + si * 4 + wid;  // sample id in [0, B*T)
    int bb = s >> 8, t = s & 255;
    size_t gbase = (size_t)s * 64;
    float xr = X[gbase + lane];
    float mr = M[gbase + lane];
    size_t ei = (size_t)t * NROW + (size_t)bb * 64 + lane;
    float re  = est_f[ei] + est_b[ei] + bp;    // RNN_estimation
    float ri  = fmaf(mr, xr - re, re);         // RNN_imputed

    float a1 = sbeta[lane];
#pragma unroll
    for (int i = 0; i < 64; ++i) {
      float xi  = bcastf(xr, i);
      float mi  = bcastf(mr, i);
      float rii = bcastf(ri, i);
      a1 = fmaf(xi,  sU [lane * FS + i], a1);
      a1 = fmaf(rii, sV1[lane * FS + i], a1);
      a1 = fmaf(mi,  sV2[lane * FS + i], a1);
    }
    // remove diagonal contributions (U, V1 have zeroed diagonals)
    a1 -= xr * sU[lane * FS + lane] + ri * sV1[lane * FS + lane];
    float hh = tanh_f(a1);

    float a2 = sbfin[lane];
#pragma unroll
    for (int k4 = 0; k4 < 16; ++k4) {
      const float4 w = wfr4[k4];
      a2 = fmaf(bcastf(hh, 4 * k4 + 0), w.x, a2);
      a2 = fmaf(bcastf(hh, 4 * k4 + 1), w.y, a2);
      a2 = fmaf(bcastf(hh, 4 * k4 + 2), w.z, a2);
      a2 = fmaf(bcastf(hh, 4 * k4 + 3), w.w, a2);
    }
    float fe = a2;                             // FCN_estimation

    out[gbase + lane] = fmaf(mr, xr - fe, fe); // M*X + (1-M)*FCN_est
    float d1 = (fe - xr) * mr; se1 = fmaf(d1, d1, se1);
    float d2 = (re - xr) * mr; se2 = fmaf(d2, d2, se2);
    sm += mr;
  }

#pragma unroll
  for (int off = 32; off; off >>= 1) {
    se1 += __shfl_xor(se1, off, 64);
    se2 += __shfl_xor(se2, off, 64);
    sm  += __shfl_xor(sm,  off, 64);
  }
  if (lane == 0) { red[0][wid] = se1; red[1][wid] = se2; red[2][wid] = sm; }
  __syncthreads();
  if (tid == 0) {
    atomicAdd(&acc[0], red[0][0] + red[0][1] + red[0][2] + red[0][3]);
    atomicAdd(&acc[1], red[1][0] + red[1][1] + red[1][2] + red[1][3]);
    atomicAdd(&acc[2], red[2][0] + red[2][1] + red[2][2] + red[2][3]);
  }
}

__global__ void loss_kernel(const float* __restrict__ acc, float* __restrict__ out_loss)
{
  if (threadIdx.x == 0 && blockIdx.x == 0) {
    float denom = acc[2] + 1e-12f;
    out_loss[0] = sqrtf(acc[0] / denom) + sqrtf(acc[1] / denom);
  }
}

extern "C" void kernel_launch(void* const* d_in, const int* in_sizes, int n_in,
                              void* d_out, int out_size, void* d_ws, size_t ws_size,
                              hipStream_t stream) {
  const float* Xf    = (const float*)d_in[0];
  const float* Mf    = (const float*)d_in[1];
  const float* Df    = (const float*)d_in[2];
  const float* Xb    = (const float*)d_in[3];
  const float* Mb    = (const float*)d_in[4];
  const float* Db    = (const float*)d_in[5];
  const float* wih_f = (const float*)d_in[6];
  const float* whh_f = (const float*)d_in[7];
  const float* bih_f = (const float*)d_in[8];
  const float* bhh_f = (const float*)d_in[9];
  const float* wih_b = (const float*)d_in[10];
  const float* whh_b = (const float*)d_in[11];
  const float* bih_b = (const float*)d_in[12];
  const float* bhh_b = (const float*)d_in[13];
  const float* Wproj = (const float*)d_in[14];
  const float* bproj = (const float*)d_in[15];
  const float* U     = (const float*)d_in[16];
  const float* V1    = (const float*)d_in[17];
  const float* V2    = (const float*)d_in[18];
  const float* beta  = (const float*)d_in[19];
  const float* Wfin  = (const float*)d_in[20];
  const float* bfin  = (const float*)d_in[21];

  float* est_f = (float*)d_ws;                         // [T, 4096] = 4 MB
  float* est_b = est_f + (size_t)T_ * NROW;            // 4 MB
  float* accp  = est_b + (size_t)T_ * NROW;            // 3 floats

  hipMemsetAsync(accp, 0, 4 * sizeof(float), stream);

  gru_kernel<<<dim3(8192), dim3(64), 0, stream>>>(
      Xf, Mf, Df, Xb, Mb, Db,
      wih_f, whh_f, bih_f, bhh_f,
      wih_b, whh_b, bih_b, bhh_b,
      Wproj, est_f, est_b);

  fcn_kernel<<<dim3(1024), dim3(256), 0, stream>>>(
      Xf, Mf, U, V1, V2, beta, Wfin, bfin, bproj,
      est_f, est_b, (float*)d_out, accp);

  loss_kernel<<<dim3(1), dim3(64), 0, stream>>>(
      accp, (float*)d_out + (size_t)B_ * T_ * F_);
}

// Round 4
// 556.487 us; speedup vs baseline: 2.8003x; 2.8003x over previous
//
#include <hip/hip_runtime.h>
#include <math.h>

#define B_ 64
#define T_ 256
#define F_ 64
#define H_ 64
#define NROW (B_ * F_) /* 4096 */

typedef short bf16x8 __attribute__((ext_vector_type(8)));
typedef float f32x4  __attribute__((ext_vector_type(4)));

__device__ __forceinline__ float bcastf(float v, int k) {
  return __int_as_float(__builtin_amdgcn_readlane(__float_as_int(v), k));
}
__device__ __forceinline__ float sigm(float x) {
  return 1.0f / (1.0f + __expf(-x));
}
__device__ __forceinline__ float tanh_f(float x) {
  float ax = fabsf(x);
  float e = __expf(-2.0f * ax);
  float r = (1.0f - e) / (1.0f + e);
  return copysignf(r, x);
}
__device__ __forceinline__ unsigned short bf16_rne(float v) {
  unsigned u = __float_as_uint(v);
  unsigned r = u + 0x7FFFu + ((u >> 16) & 1u);
  return (unsigned short)(r >> 16);
}

#define MFMA16(a, b, c) __builtin_amdgcn_mfma_f32_16x16x32_bf16((a), (b), (c), 0, 0, 0)

// Workgroup = 4 waves = 16 rows of one direction. Wave w owns units [16w,16w+16)
// for all 3 gates. h state kept as bf16 hi/lo in double-buffered LDS; recurrence
// GEMM done with mfma_f32_16x16x32_bf16 (3-term hi/lo split ~= fp32).
__global__ void __launch_bounds__(256, 2)
gru_kernel(const float* __restrict__ Xf, const float* __restrict__ Mf, const float* __restrict__ Df,
           const float* __restrict__ Xb, const float* __restrict__ Mb, const float* __restrict__ Db,
           const float* __restrict__ wih_f, const float* __restrict__ whh_f,
           const float* __restrict__ bih_f, const float* __restrict__ bhh_f,
           const float* __restrict__ wih_b, const float* __restrict__ whh_b,
           const float* __restrict__ bih_b, const float* __restrict__ bhh_b,
           const float* __restrict__ Wproj,
           float* __restrict__ est_f, float* __restrict__ est_b)
{
  __shared__ float          s_xmd[256][3][16];      // [t][{x,m,d}][row]  48 KB
  __shared__ unsigned short s_hhi[2][16][72];       // [buf][row][unit], padded stride 72
  __shared__ unsigned short s_hlo[2][16][72];
  __shared__ float          s_psum[2][4][16];       // [buf][wave][row]

  const int tid  = threadIdx.x;
  const int lane = tid & 63;
  const int wid  = tid >> 6;                        // wave 0..3
  const int dir  = blockIdx.x >> 8;                 // 0 fwd, 1 bwd
  const int n0   = (blockIdx.x & 255) * 16;         // first row of this WG
  const int b0   = n0 >> 6;
  const int f0   = n0 & 63;

  const float* X   = dir ? Xb    : Xf;
  const float* M   = dir ? Mb    : Mf;
  const float* D   = dir ? Db    : Df;
  const float* wih = dir ? wih_b : wih_f;
  const float* whh = dir ? whh_b : whh_f;
  const float* bih = dir ? bih_b : bih_f;
  const float* bhh = dir ? bhh_b : bhh_f;
  float* est       = dir ? est_b : est_f;

  const int u     = 16 * wid + (lane & 15);         // global hidden unit this lane owns (C col)
  const int ucol  = u;
  const int g8    = (lane >> 4) * 8;                // k-slot base within a k-half
  const int arow  = lane & 15;                      // A-fragment row
  const int rbase = (lane >> 4) * 4;                // C-fragment row base

  // ---- B fragments: weights for gates {r,z,n}, k-halves {0,1}, hi/lo split ----
  bf16x8 Bhi[3][2], Blo[3][2];
#pragma unroll
  for (int gt = 0; gt < 3; ++gt) {
#pragma unroll
    for (int kh = 0; kh < 2; ++kh) {
      const float* wp = &whh[(gt * 64 + u) * 64 + kh * 32 + g8];
#pragma unroll
      for (int j = 0; j < 8; ++j) {
        float v = wp[j];
        unsigned short hb = bf16_rne(v);
        float fhi = __uint_as_float((unsigned)hb << 16);
        unsigned short lb = bf16_rne(v - fhi);
        Bhi[gt][kh][j] = (short)hb;
        Blo[gt][kh][j] = (short)lb;
      }
    }
  }

  // input weights / biases for unit u
  const float wir0 = wih[(0 * 64 + u) * 3 + 0], wir1 = wih[(0 * 64 + u) * 3 + 1], wir2 = wih[(0 * 64 + u) * 3 + 2];
  const float wiz0 = wih[(1 * 64 + u) * 3 + 0], wiz1 = wih[(1 * 64 + u) * 3 + 1], wiz2 = wih[(1 * 64 + u) * 3 + 2];
  const float win0 = wih[(2 * 64 + u) * 3 + 0], win1 = wih[(2 * 64 + u) * 3 + 1], win2 = wih[(2 * 64 + u) * 3 + 2];
  const float br  = bih[0 * 64 + u] + bhh[0 * 64 + u];
  const float bz  = bih[1 * 64 + u] + bhh[1 * 64 + u];
  const float bin = bih[2 * 64 + u];
  const float bhn = bhh[2 * 64 + u];
  const float Wpu = Wproj[dir * 64 + u];

  // ---- preload the whole input sequence for these 16 rows into LDS ----
  {
    const int f  = tid & 15;
    const int t0 = tid >> 4;
    const size_t rowbase = (size_t)b0 * 256 * 64 + f0 + f;
#pragma unroll 1
    for (int c = 0; c < 16; ++c) {
      int t = t0 + 16 * c;
      size_t gidx = rowbase + (size_t)t * 64;
      s_xmd[t][0][f] = X[gidx];
      s_xmd[t][1][f] = M[gidx];
      s_xmd[t][2][f] = D[gidx];
    }
  }
  // zero h buffers
  for (int i = tid; i < 2 * 16 * 72; i += 256) {
    ((unsigned short*)s_hhi)[i] = 0;
    ((unsigned short*)s_hlo)[i] = 0;
  }
  __syncthreads();

  f32x4 hold = {0.f, 0.f, 0.f, 0.f};                // h for rows rbase..rbase+3, unit u

  for (int t = 0; t < 256; ++t) {
    const int cur = t & 1, nxt = cur ^ 1, pb = t & 1;

    // A fragments (h hi/lo) from LDS
    bf16x8 Ahi0 = *(const bf16x8*)&s_hhi[cur][arow][g8];
    bf16x8 Ahi1 = *(const bf16x8*)&s_hhi[cur][arow][32 + g8];
    bf16x8 Alo0 = *(const bf16x8*)&s_hlo[cur][arow][g8];
    bf16x8 Alo1 = *(const bf16x8*)&s_hlo[cur][arow][32 + g8];

    // inputs for this lane's 4 rows
    f32x4 xv = *(const f32x4*)&s_xmd[t][0][rbase];
    f32x4 mv = *(const f32x4*)&s_xmd[t][1][rbase];
    f32x4 dv = *(const f32x4*)&s_xmd[t][2][rbase];

    // accumulator inits: C_r/C_z = input contribs + both biases; C_n = bhh_n only
    f32x4 Cr, Cz, Cn, gin;
#pragma unroll
    for (int r = 0; r < 4; ++r) {
      Cr[r]  = fmaf(xv[r], wir0, fmaf(mv[r], wir1, fmaf(dv[r], wir2, br)));
      Cz[r]  = fmaf(xv[r], wiz0, fmaf(mv[r], wiz1, fmaf(dv[r], wiz2, bz)));
      gin[r] = fmaf(xv[r], win0, fmaf(mv[r], win1, fmaf(dv[r], win2, bin)));
      Cn[r]  = bhn;
    }

    // 18 MFMAs: per gate, 2 k-halves x {hi*hi, lo*hi, hi*lo}
    Cr = MFMA16(Ahi0, Bhi[0][0], Cr); Cr = MFMA16(Ahi1, Bhi[0][1], Cr);
    Cz = MFMA16(Ahi0, Bhi[1][0], Cz); Cz = MFMA16(Ahi1, Bhi[1][1], Cz);
    Cn = MFMA16(Ahi0, Bhi[2][0], Cn); Cn = MFMA16(Ahi1, Bhi[2][1], Cn);
    Cr = MFMA16(Alo0, Bhi[0][0], Cr); Cr = MFMA16(Alo1, Bhi[0][1], Cr);
    Cz = MFMA16(Alo0, Bhi[1][0], Cz); Cz = MFMA16(Alo1, Bhi[1][1], Cz);
    Cn = MFMA16(Alo0, Bhi[2][0], Cn); Cn = MFMA16(Alo1, Bhi[2][1], Cn);
    Cr = MFMA16(Ahi0, Blo[0][0], Cr); Cr = MFMA16(Ahi1, Blo[0][1], Cr);
    Cz = MFMA16(Ahi0, Blo[1][0], Cz); Cz = MFMA16(Ahi1, Blo[1][1], Cz);
    Cn = MFMA16(Ahi0, Blo[2][0], Cn); Cn = MFMA16(Ahi1, Blo[2][1], Cn);

    // gates, h update, publish, est partial
    float p0, p1, p2, p3;
#pragma unroll
    for (int r = 0; r < 4; ++r) {
      float rg = sigm(Cr[r]);
      float zg = sigm(Cz[r]);
      float nn = tanh_f(fmaf(rg, Cn[r], gin[r]));
      float hv = fmaf(zg, hold[r] - nn, nn);        // (1-z)*n + z*h
      hold[r] = hv;
      unsigned short hb = bf16_rne(hv);
      float fhi = __uint_as_float((unsigned)hb << 16);
      unsigned short lb = bf16_rne(hv - fhi);
      s_hhi[nxt][rbase + r][ucol] = hb;
      s_hlo[nxt][rbase + r][ucol] = lb;
      float pv = hv * Wpu;
      if (r == 0) p0 = pv; else if (r == 1) p1 = pv; else if (r == 2) p2 = pv; else p3 = pv;
    }
#pragma unroll
    for (int off = 1; off < 16; off <<= 1) {
      p0 += __shfl_xor(p0, off, 64);
      p1 += __shfl_xor(p1, off, 64);
      p2 += __shfl_xor(p2, off, 64);
      p3 += __shfl_xor(p3, off, 64);
    }
    if ((lane & 15) == 0) {
      f32x4 pv = {p0, p1, p2, p3};
      *(f32x4*)&s_psum[pb][wid][rbase] = pv;
    }

    __syncthreads();                                 // h[t+1] + psums published

    if (wid == (t & 3) && lane < 16) {               // rotating finalizer wave
      float s = s_psum[pb][0][lane] + s_psum[pb][1][lane] +
                s_psum[pb][2][lane] + s_psum[pb][3][lane];
      int tt = dir ? (255 - t) : t;
      est[(size_t)tt * NROW + n0 + lane] = s;
    }
  }
}

#define FS 65  /* padded LDS stride: 2 lanes/bank = free */

// One wave per (b,t) sample; lane = output feature o.
__global__ void __launch_bounds__(256, 2)
fcn_kernel(const float* __restrict__ X, const float* __restrict__ M,
           const float* __restrict__ U, const float* __restrict__ V1, const float* __restrict__ V2,
           const float* __restrict__ beta, const float* __restrict__ Wfin, const float* __restrict__ bfin,
           const float* __restrict__ bproj,
           const float* __restrict__ est_f, const float* __restrict__ est_b,
           float* __restrict__ out, float* __restrict__ acc)
{
  __shared__ float sU[64 * FS], sV1[64 * FS], sV2[64 * FS];
  __shared__ float sbeta[64], sbfin[64];
  __shared__ float red[3][4];
  const int tid  = threadIdx.x;
  const int lane = tid & 63;
  const int wid  = tid >> 6;

  for (int idx = tid; idx < 64 * 64; idx += 256) {
    int o = idx >> 6, i = idx & 63;
    sU [o * FS + i] = U [idx];
    sV1[o * FS + i] = V1[idx];
    sV2[o * FS + i] = V2[idx];
  }
  if (tid < 64) { sbeta[tid] = beta[tid]; sbfin[tid] = bfin[tid]; }
  __syncthreads();

  float4 wfr4[16];                         // W_fin row o in VGPRs
#pragma unroll
  for (int k4 = 0; k4 < 16; ++k4)
    wfr4[k4] = *(const float4*)&Wfin[lane * 64 + 4 * k4];

  const float bp = bproj[0];
  float se1 = 0.f, se2 = 0.f, sm = 0.f;

  const int SPB = 16;                      // samples per block
  for (int si = 0; si < SPB / 4; ++si) {
    int s  = blockIdx.x * SPB + si * 4 + wid;  // sample id in [0, B*T)
    int bb = s >> 8, t = s & 255;
    size_t gbase = (size_t)s * 64;
    float xr = X[gbase + lane];
    float mr = M[gbase + lane];
    size_t ei = (size_t)t * NROW + (size_t)bb * 64 + lane;
    float re  = est_f[ei] + est_b[ei] + bp;    // RNN_estimation
    float ri  = fmaf(mr, xr - re, re);         // RNN_imputed

    float a1 = sbeta[lane];
#pragma unroll
    for (int i = 0; i < 64; ++i) {
      float xi  = bcastf(xr, i);
      float mi  = bcastf(mr, i);
      float rii = bcastf(ri, i);
      a1 = fmaf(xi,  sU [lane * FS + i], a1);
      a1 = fmaf(rii, sV1[lane * FS + i], a1);
      a1 = fmaf(mi,  sV2[lane * FS + i], a1);
    }
    // remove diagonal contributions (U, V1 have zeroed diagonals)
    a1 -= xr * sU[lane * FS + lane] + ri * sV1[lane * FS + lane];
    float hh = tanh_f(a1);

    float a2 = sbfin[lane];
#pragma unroll
    for (int k4 = 0; k4 < 16; ++k4) {
      const float4 w = wfr4[k4];
      a2 = fmaf(bcastf(hh, 4 * k4 + 0), w.x, a2);
      a2 = fmaf(bcastf(hh, 4 * k4 + 1), w.y, a2);
      a2 = fmaf(bcastf(hh, 4 * k4 + 2), w.z, a2);
      a2 = fmaf(bcastf(hh, 4 * k4 + 3), w.w, a2);
    }
    float fe = a2;                             // FCN_estimation

    out[gbase + lane] = fmaf(mr, xr - fe, fe); // M*X + (1-M)*FCN_est
    float d1 = (fe - xr) * mr; se1 = fmaf(d1, d1, se1);
    float d2 = (re - xr) * mr; se2 = fmaf(d2, d2, se2);
    sm += mr;
  }

#pragma unroll
  for (int off = 32; off; off >>= 1) {
    se1 += __shfl_xor(se1, off, 64);
    se2 += __shfl_xor(se2, off, 64);
    sm  += __shfl_xor(sm,  off, 64);
  }
  if (lane == 0) { red[0][wid] = se1; red[1][wid] = se2; red[2][wid] = sm; }
  __syncthreads();
  if (tid == 0) {
    atomicAdd(&acc[0], red[0][0] + red[0][1] + red[0][2] + red[0][3]);
    atomicAdd(&acc[1], red[1][0] + red[1][1] + red[1][2] + red[1][3]);
    atomicAdd(&acc[2], red[2][0] + red[2][1] + red[2][2] + red[2][3]);
  }
}

__global__ void loss_kernel(const float* __restrict__ acc, float* __restrict__ out_loss)
{
  if (threadIdx.x == 0 && blockIdx.x == 0) {
    float denom = acc[2] + 1e-12f;
    out_loss[0] = sqrtf(acc[0] / denom) + sqrtf(acc[1] / denom);
  }
}

extern "C" void kernel_launch(void* const* d_in, const int* in_sizes, int n_in,
                              void* d_out, int out_size, void* d_ws, size_t ws_size,
                              hipStream_t stream) {
  const float* Xf    = (const float*)d_in[0];
  const float* Mf    = (const float*)d_in[1];
  const float* Df    = (const float*)d_in[2];
  const float* Xb    = (const float*)d_in[3];
  const float* Mb    = (const float*)d_in[4];
  const float* Db    = (const float*)d_in[5];
  const float* wih_f = (const float*)d_in[6];
  const float* whh_f = (const float*)d_in[7];
  const float* bih_f = (const float*)d_in[8];
  const float* bhh_f = (const float*)d_in[9];
  const float* wih_b = (const float*)d_in[10];
  const float* whh_b = (const float*)d_in[11];
  const float* bih_b = (const float*)d_in[12];
  const float* bhh_b = (const float*)d_in[13];
  const float* Wproj = (const float*)d_in[14];
  const float* bproj = (const float*)d_in[15];
  const float* U     = (const float*)d_in[16];
  const float* V1    = (const float*)d_in[17];
  const float* V2    = (const float*)d_in[18];
  const float* beta  = (const float*)d_in[19];
  const float* Wfin  = (const float*)d_in[20];
  const float* bfin  = (const float*)d_in[21];

  float* est_f = (float*)d_ws;                         // [T, 4096] = 4 MB
  float* est_b = est_f + (size_t)T_ * NROW;            // 4 MB
  float* accp  = est_b + (size_t)T_ * NROW;            // 3 floats

  hipMemsetAsync(accp, 0, 4 * sizeof(float), stream);

  gru_kernel<<<dim3(512), dim3(256), 0, stream>>>(
      Xf, Mf, Df, Xb, Mb, Db,
      wih_f, whh_f, bih_f, bhh_f,
      wih_b, whh_b, bih_b, bhh_b,
      Wproj, est_f, est_b);

  fcn_kernel<<<dim3(1024), dim3(256), 0, stream>>>(
      Xf, Mf, U, V1, V2, beta, Wfin, bfin, bproj,
      est_f, est_b, (float*)d_out, accp);

  loss_kernel<<<dim3(1), dim3(64), 0, stream>>>(
      accp, (float*)d_out + (size_t)B_ * T_ * F_);
}

// Round 5
// 400.881 us; speedup vs baseline: 3.8872x; 1.3882x over previous
//
#include <hip/hip_runtime.h>
#include <math.h>

#define B_ 64
#define T_ 256
#define F_ 64
#define H_ 64
#define NROW (B_ * F_) /* 4096 */

typedef short bf16x8 __attribute__((ext_vector_type(8)));
typedef float f32x4  __attribute__((ext_vector_type(4)));

__device__ __forceinline__ float bcastf(float v, int k) {
  return __int_as_float(__builtin_amdgcn_readlane(__float_as_int(v), k));
}
__device__ __forceinline__ float rcp_f(float x) {
  float r; asm("v_rcp_f32 %0, %1" : "=v"(r) : "v"(x)); return r;
}
__device__ __forceinline__ float sigm(float x) {
  return rcp_f(1.0f + __expf(-x));          // 1/(1+e^-x), raw v_rcp (~1e-7 rel)
}
__device__ __forceinline__ float tanh_f(float y) {
  return fmaf(-2.0f, rcp_f(1.0f + __expf(2.0f * y)), 1.0f);  // 1 - 2/(1+e^2y)
}
__device__ __forceinline__ unsigned short bf16_rne(float v) {
  unsigned u = __float_as_uint(v);
  unsigned r = u + 0x7FFFu + ((u >> 16) & 1u);
  return (unsigned short)(r >> 16);
}

#define MFMA16(a, b, c) __builtin_amdgcn_mfma_f32_16x16x32_bf16((a), (b), (c), 0, 0, 0)

// Workgroup = 4 waves = 16 rows of one direction. Wave w owns units [16w,16w+16)
// for all 3 gates. h state kept as bf16 hi/lo in double-buffered LDS; recurrence
// GEMM via mfma_f32_16x16x32_bf16 (3-term hi/lo split ~= fp32). est computed by
// a rotating wave with 6 extra MFMAs against a W_proj B-fragment (col 0 only) --
// no cross-lane reduce chain.
__global__ void __launch_bounds__(256, 2)
gru_kernel(const float* __restrict__ Xf, const float* __restrict__ Mf, const float* __restrict__ Df,
           const float* __restrict__ Xb, const float* __restrict__ Mb, const float* __restrict__ Db,
           const float* __restrict__ wih_f, const float* __restrict__ whh_f,
           const float* __restrict__ bih_f, const float* __restrict__ bhh_f,
           const float* __restrict__ wih_b, const float* __restrict__ whh_b,
           const float* __restrict__ bih_b, const float* __restrict__ bhh_b,
           const float* __restrict__ Wproj,
           float* __restrict__ est_f, float* __restrict__ est_b)
{
  __shared__ float          s_xmd[256][3][16];      // [t][{x,m,d}][row]  48 KB
  __shared__ unsigned short s_hhi[2][16][72];       // [buf][row][unit], padded stride 72
  __shared__ unsigned short s_hlo[2][16][72];

  const int tid  = threadIdx.x;
  const int lane = tid & 63;
  const int wid  = tid >> 6;                        // wave 0..3
  const int dir  = blockIdx.x >> 8;                 // 0 fwd, 1 bwd
  const int n0   = (blockIdx.x & 255) * 16;         // first row of this WG
  const int b0   = n0 >> 6;
  const int f0   = n0 & 63;

  const float* X   = dir ? Xb    : Xf;
  const float* M   = dir ? Mb    : Mf;
  const float* D   = dir ? Db    : Df;
  const float* wih = dir ? wih_b : wih_f;
  const float* whh = dir ? whh_b : whh_f;
  const float* bih = dir ? bih_b : bih_f;
  const float* bhh = dir ? bhh_b : bhh_f;
  float* est       = dir ? est_b : est_f;

  const int u     = 16 * wid + (lane & 15);         // global hidden unit this lane owns (C col)
  const int ucol  = u;
  const int g8    = (lane >> 4) * 8;                // k-slot base within a k-half
  const int arow  = lane & 15;                      // A-fragment row
  const int rbase = (lane >> 4) * 4;                // C-fragment row base

  // ---- B fragments: weights for gates {r,z,n}, k-halves {0,1}, hi/lo split ----
  bf16x8 Bhi[3][2], Blo[3][2];
#pragma unroll
  for (int gt = 0; gt < 3; ++gt) {
#pragma unroll
    for (int kh = 0; kh < 2; ++kh) {
      const float* wp = &whh[(gt * 64 + u) * 64 + kh * 32 + g8];
#pragma unroll
      for (int j = 0; j < 8; ++j) {
        float v = wp[j];
        unsigned short hb = bf16_rne(v);
        float fhi = __uint_as_float((unsigned)hb << 16);
        unsigned short lb = bf16_rne(v - fhi);
        Bhi[gt][kh][j] = (short)hb;
        Blo[gt][kh][j] = (short)lb;
      }
    }
  }

  // ---- W_proj B fragments: column 0 = Wp, other cols 0 (for est MFMA) ----
  bf16x8 Bp_hi0, Bp_hi1, Bp_lo0, Bp_lo1;
#pragma unroll
  for (int j = 0; j < 8; ++j) {
    float v0 = ((lane & 15) == 0) ? Wproj[dir * 64 + 0 * 32 + g8 + j] : 0.0f;
    float v1 = ((lane & 15) == 0) ? Wproj[dir * 64 + 1 * 32 + g8 + j] : 0.0f;
    unsigned short h0 = bf16_rne(v0), h1 = bf16_rne(v1);
    float f0h = __uint_as_float((unsigned)h0 << 16);
    float f1h = __uint_as_float((unsigned)h1 << 16);
    Bp_hi0[j] = (short)h0; Bp_hi1[j] = (short)h1;
    Bp_lo0[j] = (short)bf16_rne(v0 - f0h);
    Bp_lo1[j] = (short)bf16_rne(v1 - f1h);
  }

  // input weights / biases for unit u
  const float wir0 = wih[(0 * 64 + u) * 3 + 0], wir1 = wih[(0 * 64 + u) * 3 + 1], wir2 = wih[(0 * 64 + u) * 3 + 2];
  const float wiz0 = wih[(1 * 64 + u) * 3 + 0], wiz1 = wih[(1 * 64 + u) * 3 + 1], wiz2 = wih[(1 * 64 + u) * 3 + 2];
  const float win0 = wih[(2 * 64 + u) * 3 + 0], win1 = wih[(2 * 64 + u) * 3 + 1], win2 = wih[(2 * 64 + u) * 3 + 2];
  const float br  = bih[0 * 64 + u] + bhh[0 * 64 + u];
  const float bz  = bih[1 * 64 + u] + bhh[1 * 64 + u];
  const float bin = bih[2 * 64 + u];
  const float bhn = bhh[2 * 64 + u];

  // ---- preload the whole input sequence for these 16 rows into LDS ----
  {
    const int f  = tid & 15;
    const int t0 = tid >> 4;
    const size_t rowbase = (size_t)b0 * 256 * 64 + f0 + f;
#pragma unroll 1
    for (int c = 0; c < 16; ++c) {
      int t = t0 + 16 * c;
      size_t gidx = rowbase + (size_t)t * 64;
      s_xmd[t][0][f] = X[gidx];
      s_xmd[t][1][f] = M[gidx];
      s_xmd[t][2][f] = D[gidx];
    }
  }
  // zero h buffers
  for (int i = tid; i < 2 * 16 * 72; i += 256) {
    ((unsigned short*)s_hhi)[i] = 0;
    ((unsigned short*)s_hlo)[i] = 0;
  }
  __syncthreads();

  f32x4 hold = {0.f, 0.f, 0.f, 0.f};                // h for rows rbase..rbase+3, unit u

#pragma unroll 2
  for (int t = 0; t < 256; ++t) {
    const int cur = t & 1, nxt = cur ^ 1;

    // A fragments (h hi/lo = hs[t-1]) from LDS
    bf16x8 Ahi0 = *(const bf16x8*)&s_hhi[cur][arow][g8];
    bf16x8 Ahi1 = *(const bf16x8*)&s_hhi[cur][arow][32 + g8];
    bf16x8 Alo0 = *(const bf16x8*)&s_hlo[cur][arow][g8];
    bf16x8 Alo1 = *(const bf16x8*)&s_hlo[cur][arow][32 + g8];

    // est[t-1] = hs[t-1] . Wp  -- rotating wave, 6 MFMAs, col 0 of C
    if (t > 0 && wid == ((t - 1) & 3)) {
      f32x4 Cp = {0.f, 0.f, 0.f, 0.f};
      Cp = MFMA16(Ahi0, Bp_hi0, Cp); Cp = MFMA16(Ahi1, Bp_hi1, Cp);
      Cp = MFMA16(Alo0, Bp_hi0, Cp); Cp = MFMA16(Alo1, Bp_hi1, Cp);
      Cp = MFMA16(Ahi0, Bp_lo0, Cp); Cp = MFMA16(Ahi1, Bp_lo1, Cp);
      if ((lane & 15) == 0) {
        int tp = t - 1;
        int tt = dir ? (255 - tp) : tp;
        *(f32x4*)&est[(size_t)tt * NROW + n0 + rbase] = Cp;
      }
    }

    // inputs for this lane's 4 rows
    f32x4 xv = *(const f32x4*)&s_xmd[t][0][rbase];
    f32x4 mv = *(const f32x4*)&s_xmd[t][1][rbase];
    f32x4 dv = *(const f32x4*)&s_xmd[t][2][rbase];

    // accumulator inits: C_r/C_z = input contribs + both biases; C_n = bhh_n only
    f32x4 Cr, Cz, Cn, gin;
#pragma unroll
    for (int r = 0; r < 4; ++r) {
      Cr[r]  = fmaf(xv[r], wir0, fmaf(mv[r], wir1, fmaf(dv[r], wir2, br)));
      Cz[r]  = fmaf(xv[r], wiz0, fmaf(mv[r], wiz1, fmaf(dv[r], wiz2, bz)));
      gin[r] = fmaf(xv[r], win0, fmaf(mv[r], win1, fmaf(dv[r], win2, bin)));
      Cn[r]  = bhn;
    }

    // 18 MFMAs: per gate, 2 k-halves x {hi*hi, lo*hi, hi*lo}
    Cr = MFMA16(Ahi0, Bhi[0][0], Cr); Cr = MFMA16(Ahi1, Bhi[0][1], Cr);
    Cz = MFMA16(Ahi0, Bhi[1][0], Cz); Cz = MFMA16(Ahi1, Bhi[1][1], Cz);
    Cn = MFMA16(Ahi0, Bhi[2][0], Cn); Cn = MFMA16(Ahi1, Bhi[2][1], Cn);
    Cr = MFMA16(Alo0, Bhi[0][0], Cr); Cr = MFMA16(Alo1, Bhi[0][1], Cr);
    Cz = MFMA16(Alo0, Bhi[1][0], Cz); Cz = MFMA16(Alo1, Bhi[1][1], Cz);
    Cn = MFMA16(Alo0, Bhi[2][0], Cn); Cn = MFMA16(Alo1, Bhi[2][1], Cn);
    Cr = MFMA16(Ahi0, Blo[0][0], Cr); Cr = MFMA16(Ahi1, Blo[0][1], Cr);
    Cz = MFMA16(Ahi0, Blo[1][0], Cz); Cz = MFMA16(Ahi1, Blo[1][1], Cz);
    Cn = MFMA16(Ahi0, Blo[2][0], Cn); Cn = MFMA16(Ahi1, Blo[2][1], Cn);

    // gates, h update, publish
#pragma unroll
    for (int r = 0; r < 4; ++r) {
      float rg = sigm(Cr[r]);
      float zg = sigm(Cz[r]);
      float nn = tanh_f(fmaf(rg, Cn[r], gin[r]));
      float hv = fmaf(zg, hold[r] - nn, nn);        // (1-z)*n + z*h
      hold[r] = hv;
      unsigned short hb = bf16_rne(hv);
      float fhi = __uint_as_float((unsigned)hb << 16);
      unsigned short lb = bf16_rne(hv - fhi);
      s_hhi[nxt][rbase + r][ucol] = hb;
      s_hlo[nxt][rbase + r][ucol] = lb;
    }

    __syncthreads();                                 // h[t] published for t+1
  }

  // epilogue: est[255] from the final h (in buffer 0)
  if (wid == 3) {
    bf16x8 Ahi0 = *(const bf16x8*)&s_hhi[0][arow][g8];
    bf16x8 Ahi1 = *(const bf16x8*)&s_hhi[0][arow][32 + g8];
    bf16x8 Alo0 = *(const bf16x8*)&s_hlo[0][arow][g8];
    bf16x8 Alo1 = *(const bf16x8*)&s_hlo[0][arow][32 + g8];
    f32x4 Cp = {0.f, 0.f, 0.f, 0.f};
    Cp = MFMA16(Ahi0, Bp_hi0, Cp); Cp = MFMA16(Ahi1, Bp_hi1, Cp);
    Cp = MFMA16(Alo0, Bp_hi0, Cp); Cp = MFMA16(Alo1, Bp_hi1, Cp);
    Cp = MFMA16(Ahi0, Bp_lo0, Cp); Cp = MFMA16(Ahi1, Bp_lo1, Cp);
    if ((lane & 15) == 0) {
      int tt = dir ? 0 : 255;
      *(f32x4*)&est[(size_t)tt * NROW + n0 + rbase] = Cp;
    }
  }
}

#define FS 65  /* padded LDS stride: 2 lanes/bank = free */

// One wave per (b,t) sample; lane = output feature o.
__global__ void __launch_bounds__(256, 2)
fcn_kernel(const float* __restrict__ X, const float* __restrict__ M,
           const float* __restrict__ U, const float* __restrict__ V1, const float* __restrict__ V2,
           const float* __restrict__ beta, const float* __restrict__ Wfin, const float* __restrict__ bfin,
           const float* __restrict__ bproj,
           const float* __restrict__ est_f, const float* __restrict__ est_b,
           float* __restrict__ out, float* __restrict__ acc)
{
  __shared__ float sU[64 * FS], sV1[64 * FS], sV2[64 * FS];
  __shared__ float sbeta[64], sbfin[64];
  __shared__ float red[3][4];
  const int tid  = threadIdx.x;
  const int lane = tid & 63;
  const int wid  = tid >> 6;

  for (int idx = tid; idx < 64 * 64; idx += 256) {
    int o = idx >> 6, i = idx & 63;
    sU [o * FS + i] = U [idx];
    sV1[o * FS + i] = V1[idx];
    sV2[o * FS + i] = V2[idx];
  }
  if (tid < 64) { sbeta[tid] = beta[tid]; sbfin[tid] = bfin[tid]; }
  __syncthreads();

  float4 wfr4[16];                         // W_fin row o in VGPRs
#pragma unroll
  for (int k4 = 0; k4 < 16; ++k4)
    wfr4[k4] = *(const float4*)&Wfin[lane * 64 + 4 * k4];

  const float bp = bproj[0];
  float se1 = 0.f, se2 = 0.f, sm = 0.f;

  const int SPB = 16;                      // samples per block
  for (int si = 0; si < SPB / 4; ++si) {
    int s  = blockIdx.x * SPB + si * 4 + wid;  // sample id in [0, B*T)
    int bb = s >> 8, t = s & 255;
    size_t gbase = (size_t)s * 64;
    float xr = X[gbase + lane];
    float mr = M[gbase + lane];
    size_t ei = (size_t)t * NROW + (size_t)bb * 64 + lane;
    float re  = est_f[ei] + est_b[ei] + bp;    // RNN_estimation
    float ri  = fmaf(mr, xr - re, re);         // RNN_imputed

    float a1 = sbeta[lane];
#pragma unroll
    for (int i = 0; i < 64; ++i) {
      float xi  = bcastf(xr, i);
      float mi  = bcastf(mr, i);
      float rii = bcastf(ri, i);
      a1 = fmaf(xi,  sU [lane * FS + i], a1);
      a1 = fmaf(rii, sV1[lane * FS + i], a1);
      a1 = fmaf(mi,  sV2[lane * FS + i], a1);
    }
    // remove diagonal contributions (U, V1 have zeroed diagonals)
    a1 -= xr * sU[lane * FS + lane] + ri * sV1[lane * FS + lane];
    float hh = tanhf(a1);

    float a2 = sbfin[lane];
#pragma unroll
    for (int k4 = 0; k4 < 16; ++k4) {
      const float4 w = wfr4[k4];
      a2 = fmaf(bcastf(hh, 4 * k4 + 0), w.x, a2);
      a2 = fmaf(bcastf(hh, 4 * k4 + 1), w.y, a2);
      a2 = fmaf(bcastf(hh, 4 * k4 + 2), w.z, a2);
      a2 = fmaf(bcastf(hh, 4 * k4 + 3), w.w, a2);
    }
    float fe = a2;                             // FCN_estimation

    out[gbase + lane] = fmaf(mr, xr - fe, fe); // M*X + (1-M)*FCN_est
    float d1 = (fe - xr) * mr; se1 = fmaf(d1, d1, se1);
    float d2 = (re - xr) * mr; se2 = fmaf(d2, d2, se2);
    sm += mr;
  }

#pragma unroll
  for (int off = 32; off; off >>= 1) {
    se1 += __shfl_xor(se1, off, 64);
    se2 += __shfl_xor(se2, off, 64);
    sm  += __shfl_xor(sm,  off, 64);
  }
  if (lane == 0) { red[0][wid] = se1; red[1][wid] = se2; red[2][wid] = sm; }
  __syncthreads();
  if (tid == 0) {
    atomicAdd(&acc[0], red[0][0] + red[0][1] + red[0][2] + red[0][3]);
    atomicAdd(&acc[1], red[1][0] + red[1][1] + red[1][2] + red[1][3]);
    atomicAdd(&acc[2], red[2][0] + red[2][1] + red[2][2] + red[2][3]);
  }
}

__global__ void loss_kernel(const float* __restrict__ acc, float* __restrict__ out_loss)
{
  if (threadIdx.x == 0 && blockIdx.x == 0) {
    float denom = acc[2] + 1e-12f;
    out_loss[0] = sqrtf(acc[0] / denom) + sqrtf(acc[1] / denom);
  }
}

extern "C" void kernel_launch(void* const* d_in, const int* in_sizes, int n_in,
                              void* d_out, int out_size, void* d_ws, size_t ws_size,
                              hipStream_t stream) {
  const float* Xf    = (const float*)d_in[0];
  const float* Mf    = (const float*)d_in[1];
  const float* Df    = (const float*)d_in[2];
  const float* Xb    = (const float*)d_in[3];
  const float* Mb    = (const float*)d_in[4];
  const float* Db    = (const float*)d_in[5];
  const float* wih_f = (const float*)d_in[6];
  const float* whh_f = (const float*)d_in[7];
  const float* bih_f = (const float*)d_in[8];
  const float* bhh_f = (const float*)d_in[9];
  const float* wih_b = (const float*)d_in[10];
  const float* whh_b = (const float*)d_in[11];
  const float* bih_b = (const float*)d_in[12];
  const float* bhh_b = (const float*)d_in[13];
  const float* Wproj = (const float*)d_in[14];
  const float* bproj = (const float*)d_in[15];
  const float* U     = (const float*)d_in[16];
  const float* V1    = (const float*)d_in[17];
  const float* V2    = (const float*)d_in[18];
  const float* beta  = (const float*)d_in[19];
  const float* Wfin  = (const float*)d_in[20];
  const float* bfin  = (const float*)d_in[21];

  float* est_f = (float*)d_ws;                         // [T, 4096] = 4 MB
  float* est_b = est_f + (size_t)T_ * NROW;            // 4 MB
  float* accp  = est_b + (size_t)T_ * NROW;            // 3 floats

  hipMemsetAsync(accp, 0, 4 * sizeof(float), stream);

  gru_kernel<<<dim3(512), dim3(256), 0, stream>>>(
      Xf, Mf, Df, Xb, Mb, Db,
      wih_f, whh_f, bih_f, bhh_f,
      wih_b, whh_b, bih_b, bhh_b,
      Wproj, est_f, est_b);

  fcn_kernel<<<dim3(1024), dim3(256), 0, stream>>>(
      Xf, Mf, U, V1, V2, beta, Wfin, bfin, bproj,
      est_f, est_b, (float*)d_out, accp);

  loss_kernel<<<dim3(1), dim3(64), 0, stream>>>(
      accp, (float*)d_out + (size_t)B_ * T_ * F_);
}

// Round 6
// 324.464 us; speedup vs baseline: 4.8027x; 1.2355x over previous
//
#include <hip/hip_runtime.h>
#include <math.h>

#define B_ 64
#define T_ 256
#define F_ 64
#define H_ 64
#define NROW (B_ * F_) /* 4096 */

typedef short bf16x8 __attribute__((ext_vector_type(8)));
typedef float f32x4  __attribute__((ext_vector_type(4)));

__device__ __forceinline__ float rcp_f(float x) {
  float r; asm("v_rcp_f32 %0, %1" : "=v"(r) : "v"(x)); return r;
}
__device__ __forceinline__ float sigm(float x) {
  return rcp_f(1.0f + __expf(-x));
}
__device__ __forceinline__ float tanh_f(float y) {
  return fmaf(-2.0f, rcp_f(1.0f + __expf(2.0f * y)), 1.0f);
}
__device__ __forceinline__ unsigned short bf16_rne(float v) {
  unsigned u = __float_as_uint(v);
  unsigned r = u + 0x7FFFu + ((u >> 16) & 1u);
  return (unsigned short)(r >> 16);
}

#define MFMA16(a, b, c) __builtin_amdgcn_mfma_f32_16x16x32_bf16((a), (b), (c), 0, 0, 0)

// Workgroup = 4 waves = 16 rows of one direction. Wave w owns units [16w,16w+16).
// h kept f32 in registers (hold); GEMM input h is bf16 (single, no lo-split --
// error enters as ~3e-4/step damped noise, does not accumulate in h itself).
// Weights keep hi/lo split (systematic error matters). 12 MFMAs/step/wave.
__global__ void __launch_bounds__(256, 2)
gru_kernel(const float* __restrict__ Xf, const float* __restrict__ Mf, const float* __restrict__ Df,
           const float* __restrict__ Xb, const float* __restrict__ Mb, const float* __restrict__ Db,
           const float* __restrict__ wih_f, const float* __restrict__ whh_f,
           const float* __restrict__ bih_f, const float* __restrict__ bhh_f,
           const float* __restrict__ wih_b, const float* __restrict__ whh_b,
           const float* __restrict__ bih_b, const float* __restrict__ bhh_b,
           const float* __restrict__ Wproj,
           float* __restrict__ est_f, float* __restrict__ est_b)
{
  __shared__ float          s_xmd[256][3][16];      // [t][{x,m,d}][row]  48 KB
  __shared__ unsigned short s_h[2][16][72];         // [buf][row][unit], padded stride 72

  const int tid  = threadIdx.x;
  const int lane = tid & 63;
  const int wid  = tid >> 6;                        // wave 0..3
  const int dir  = blockIdx.x >> 8;                 // 0 fwd, 1 bwd
  const int n0   = (blockIdx.x & 255) * 16;         // first row of this WG
  const int b0   = n0 >> 6;
  const int f0   = n0 & 63;

  const float* X   = dir ? Xb    : Xf;
  const float* M   = dir ? Mb    : Mf;
  const float* D   = dir ? Db    : Df;
  const float* wih = dir ? wih_b : wih_f;
  const float* whh = dir ? whh_b : whh_f;
  const float* bih = dir ? bih_b : bih_f;
  const float* bhh = dir ? bhh_b : bhh_f;
  float* est       = dir ? est_b : est_f;

  const int u     = 16 * wid + (lane & 15);         // global hidden unit (C col)
  const int ucol  = u;
  const int g8    = (lane >> 4) * 8;                // k-slot base within a k-half
  const int arow  = lane & 15;                      // A-fragment row
  const int rbase = (lane >> 4) * 4;                // C-fragment row base

  // ---- B fragments: weights, hi/lo split ----
  bf16x8 Bhi[3][2], Blo[3][2];
#pragma unroll
  for (int gt = 0; gt < 3; ++gt) {
#pragma unroll
    for (int kh = 0; kh < 2; ++kh) {
      const float* wp = &whh[(gt * 64 + u) * 64 + kh * 32 + g8];
#pragma unroll
      for (int j = 0; j < 8; ++j) {
        float v = wp[j];
        unsigned short hb = bf16_rne(v);
        float fhi = __uint_as_float((unsigned)hb << 16);
        Bhi[gt][kh][j] = (short)hb;
        Blo[gt][kh][j] = (short)bf16_rne(v - fhi);
      }
    }
  }

  // ---- W_proj B fragments: column 0 only ----
  bf16x8 Bp_hi0, Bp_hi1, Bp_lo0, Bp_lo1;
#pragma unroll
  for (int j = 0; j < 8; ++j) {
    float v0 = ((lane & 15) == 0) ? Wproj[dir * 64 + 0 * 32 + g8 + j] : 0.0f;
    float v1 = ((lane & 15) == 0) ? Wproj[dir * 64 + 1 * 32 + g8 + j] : 0.0f;
    unsigned short h0 = bf16_rne(v0), h1 = bf16_rne(v1);
    float f0h = __uint_as_float((unsigned)h0 << 16);
    float f1h = __uint_as_float((unsigned)h1 << 16);
    Bp_hi0[j] = (short)h0; Bp_hi1[j] = (short)h1;
    Bp_lo0[j] = (short)bf16_rne(v0 - f0h);
    Bp_lo1[j] = (short)bf16_rne(v1 - f1h);
  }

  const float wir0 = wih[(0 * 64 + u) * 3 + 0], wir1 = wih[(0 * 64 + u) * 3 + 1], wir2 = wih[(0 * 64 + u) * 3 + 2];
  const float wiz0 = wih[(1 * 64 + u) * 3 + 0], wiz1 = wih[(1 * 64 + u) * 3 + 1], wiz2 = wih[(1 * 64 + u) * 3 + 2];
  const float win0 = wih[(2 * 64 + u) * 3 + 0], win1 = wih[(2 * 64 + u) * 3 + 1], win2 = wih[(2 * 64 + u) * 3 + 2];
  const float br  = bih[0 * 64 + u] + bhh[0 * 64 + u];
  const float bz  = bih[1 * 64 + u] + bhh[1 * 64 + u];
  const float bin = bih[2 * 64 + u];
  const float bhn = bhh[2 * 64 + u];

  // ---- preload the whole input sequence for these 16 rows into LDS ----
  {
    const int f  = tid & 15;
    const int t0 = tid >> 4;
    const size_t rowbase = (size_t)b0 * 256 * 64 + f0 + f;
#pragma unroll 1
    for (int c = 0; c < 16; ++c) {
      int t = t0 + 16 * c;
      size_t gidx = rowbase + (size_t)t * 64;
      s_xmd[t][0][f] = X[gidx];
      s_xmd[t][1][f] = M[gidx];
      s_xmd[t][2][f] = D[gidx];
    }
  }
  for (int i = tid; i < 2 * 16 * 72; i += 256)
    ((unsigned short*)s_h)[i] = 0;
  __syncthreads();

  f32x4 hold = {0.f, 0.f, 0.f, 0.f};

#pragma unroll 2
  for (int t = 0; t < 256; ++t) {
    const int cur = t & 1, nxt = cur ^ 1;

    bf16x8 Ahi0 = *(const bf16x8*)&s_h[cur][arow][g8];
    bf16x8 Ahi1 = *(const bf16x8*)&s_h[cur][arow][32 + g8];

    // est[t-1] = hs[t-1] . Wp  -- rotating wave, 4 MFMAs
    if (t > 0 && wid == ((t - 1) & 3)) {
      f32x4 Cp = {0.f, 0.f, 0.f, 0.f};
      Cp = MFMA16(Ahi0, Bp_hi0, Cp); Cp = MFMA16(Ahi1, Bp_hi1, Cp);
      Cp = MFMA16(Ahi0, Bp_lo0, Cp); Cp = MFMA16(Ahi1, Bp_lo1, Cp);
      if ((lane & 15) == 0) {
        int tp = t - 1;
        int tt = dir ? (255 - tp) : tp;
        *(f32x4*)&est[(size_t)tt * NROW + n0 + rbase] = Cp;
      }
    }

    f32x4 xv = *(const f32x4*)&s_xmd[t][0][rbase];
    f32x4 mv = *(const f32x4*)&s_xmd[t][1][rbase];
    f32x4 dv = *(const f32x4*)&s_xmd[t][2][rbase];

    f32x4 Cr, Cz, Cn, gin;
#pragma unroll
    for (int r = 0; r < 4; ++r) {
      Cr[r]  = fmaf(xv[r], wir0, fmaf(mv[r], wir1, fmaf(dv[r], wir2, br)));
      Cz[r]  = fmaf(xv[r], wiz0, fmaf(mv[r], wiz1, fmaf(dv[r], wiz2, bz)));
      gin[r] = fmaf(xv[r], win0, fmaf(mv[r], win1, fmaf(dv[r], win2, bin)));
      Cn[r]  = bhn;
    }

    // 12 MFMAs: per gate, 2 k-halves x {hi(A)*hi(B), hi(A)*lo(B)}
    Cr = MFMA16(Ahi0, Bhi[0][0], Cr); Cr = MFMA16(Ahi1, Bhi[0][1], Cr);
    Cz = MFMA16(Ahi0, Bhi[1][0], Cz); Cz = MFMA16(Ahi1, Bhi[1][1], Cz);
    Cn = MFMA16(Ahi0, Bhi[2][0], Cn); Cn = MFMA16(Ahi1, Bhi[2][1], Cn);
    Cr = MFMA16(Ahi0, Blo[0][0], Cr); Cr = MFMA16(Ahi1, Blo[0][1], Cr);
    Cz = MFMA16(Ahi0, Blo[1][0], Cz); Cz = MFMA16(Ahi1, Blo[1][1], Cz);
    Cn = MFMA16(Ahi0, Blo[2][0], Cn); Cn = MFMA16(Ahi1, Blo[2][1], Cn);

#pragma unroll
    for (int r = 0; r < 4; ++r) {
      float rg = sigm(Cr[r]);
      float zg = sigm(Cz[r]);
      float nn = tanh_f(fmaf(rg, Cn[r], gin[r]));
      float hv = fmaf(zg, hold[r] - nn, nn);        // (1-z)*n + z*h
      hold[r] = hv;
      s_h[nxt][rbase + r][ucol] = bf16_rne(hv);
    }

    __syncthreads();
  }

  // epilogue: est[255] from the final h (in buffer 0)
  if (wid == 3) {
    bf16x8 Ahi0 = *(const bf16x8*)&s_h[0][arow][g8];
    bf16x8 Ahi1 = *(const bf16x8*)&s_h[0][arow][32 + g8];
    f32x4 Cp = {0.f, 0.f, 0.f, 0.f};
    Cp = MFMA16(Ahi0, Bp_hi0, Cp); Cp = MFMA16(Ahi1, Bp_hi1, Cp);
    Cp = MFMA16(Ahi0, Bp_lo0, Cp); Cp = MFMA16(Ahi1, Bp_lo1, Cp);
    if ((lane & 15) == 0) {
      int tt = dir ? 0 : 255;
      *(f32x4*)&est[(size_t)tt * NROW + n0 + rbase] = Cp;
    }
  }
}

// FCN via MFMA. WG = 64 samples (4 waves x 16). A = [X | RI | M] (K=192) bf16,
// W1 = [U o m ; V1 o m ; V2] bf16 (diag masked at staging). GEMM1: 24 MFMA/wave;
// tanh; wave-local sH; GEMM2: 8 MFMA/wave. Loss partials in staging/epilogue.
__global__ void __launch_bounds__(256, 2)
fcn_kernel(const float* __restrict__ X, const float* __restrict__ M,
           const float* __restrict__ U, const float* __restrict__ V1, const float* __restrict__ V2,
           const float* __restrict__ beta, const float* __restrict__ Wfin, const float* __restrict__ bfin,
           const float* __restrict__ bproj,
           const float* __restrict__ est_f, const float* __restrict__ est_b,
           float* __restrict__ out, float* __restrict__ acc)
{
  __shared__ unsigned short sA[64][200];    // [sample][k] k:0-63 X, 64-127 RI, 128-191 M
  __shared__ unsigned short sW1[64][200];   // [o][k]
  __shared__ unsigned short sW2[64][72];    // [o][j]  Wfin
  __shared__ unsigned short sH[64][72];     // [sample][j]  h1 bf16
  __shared__ float sbeta[64], sbfin[64];
  __shared__ float red[3][4];

  const int tid  = threadIdx.x;
  const int lane = tid & 63;
  const int wid  = tid >> 6;
  const int wg   = blockIdx.x;              // 0..255
  const int bb   = wg >> 2;                 // batch index (const per WG)
  const int t0   = (wg & 3) * 64;           // first timestep

  // ---- stage W1 (diag-masked), W2 ----
  for (int idx = tid; idx < 4096; idx += 256) {
    int o = idx >> 6, i = idx & 63;
    sW1[o][i]       = bf16_rne((i == o) ? 0.f : U[idx]);
    sW1[o][64 + i]  = bf16_rne((i == o) ? 0.f : V1[idx]);
    sW1[o][128 + i] = bf16_rne(V2[idx]);
    sW2[o][i]       = bf16_rne(Wfin[idx]);
  }
  if (tid < 64) { sbeta[tid] = beta[tid]; sbfin[tid] = bfin[tid]; }

  // ---- stage A + RNN-loss partials ----
  const float bp = bproj[0];
  float se1 = 0.f, se2 = 0.f, sm = 0.f;
  {
    const int i = lane;
#pragma unroll 1
    for (int p = 0; p < 16; ++p) {
      int s = wid + 4 * p;                  // sample within WG
      int t = t0 + s;
      size_t gidx = ((size_t)bb * 256 + t) * 64 + i;
      float x = X[gidx], m = M[gidx];
      size_t ei = (size_t)t * NROW + bb * 64 + i;
      float re = est_f[ei] + est_b[ei] + bp;
      float ri = fmaf(m, x - re, re);
      sA[s][i]       = bf16_rne(x);
      sA[s][64 + i]  = bf16_rne(ri);
      sA[s][128 + i] = bf16_rne(m);
      float d2 = (re - x) * m;
      se2 = fmaf(d2, d2, se2); sm += m;
    }
  }
  __syncthreads();

  const int srow0 = wid * 16;
  const int arow  = lane & 15;
  const int g8    = (lane >> 4) * 8;
  const int rb    = srow0 + (lane >> 4) * 4;

  // ---- GEMM1: [16 samples x 192] @ W1^T -> 64 outs ----
  bf16x8 Af[6];
#pragma unroll
  for (int kh = 0; kh < 6; ++kh)
    Af[kh] = *(const bf16x8*)&sA[srow0 + arow][kh * 32 + g8];

  f32x4 Hc[4];
#pragma unroll
  for (int c = 0; c < 4; ++c) {
    float b0 = sbeta[c * 16 + arow];
    f32x4 C = {b0, b0, b0, b0};
#pragma unroll
    for (int kh = 0; kh < 6; ++kh) {
      bf16x8 Bf = *(const bf16x8*)&sW1[c * 16 + arow][kh * 32 + g8];
      C = MFMA16(Af[kh], Bf, C);
    }
    Hc[c] = C;
  }

  // tanh + publish h1 (bf16). C layout: col = c*16+arow, row = rb + r.
#pragma unroll
  for (int c = 0; c < 4; ++c)
#pragma unroll
    for (int r = 0; r < 4; ++r)
      sH[rb + r][c * 16 + arow] = bf16_rne(tanh_f(Hc[c][r]));
  __syncthreads();

  // ---- GEMM2: h1 @ Wfin^T ----
  bf16x8 A2[2];
#pragma unroll
  for (int kh = 0; kh < 2; ++kh)
    A2[kh] = *(const bf16x8*)&sH[srow0 + arow][kh * 32 + g8];

  f32x4 FE[4];
#pragma unroll
  for (int c = 0; c < 4; ++c) {
    float b0 = sbfin[c * 16 + arow];
    f32x4 C = {b0, b0, b0, b0};
#pragma unroll
    for (int kh = 0; kh < 2; ++kh) {
      bf16x8 B2 = *(const bf16x8*)&sW2[c * 16 + arow][kh * 32 + g8];
      C = MFMA16(A2[kh], B2, C);
    }
    FE[c] = C;
  }

  // ---- epilogue: imputed output + FCN-loss partials ----
#pragma unroll
  for (int c = 0; c < 4; ++c) {
#pragma unroll
    for (int r = 0; r < 4; ++r) {
      int s = rb + r;
      int o = c * 16 + arow;
      size_t gidx = ((size_t)bb * 256 + (t0 + s)) * 64 + o;
      float x = X[gidx], m = M[gidx];
      float fe = FE[c][r];
      out[gidx] = fmaf(m, x - fe, fe);
      float d1 = (fe - x) * m;
      se1 = fmaf(d1, d1, se1);
    }
  }

#pragma unroll
  for (int off = 32; off; off >>= 1) {
    se1 += __shfl_xor(se1, off, 64);
    se2 += __shfl_xor(se2, off, 64);
    sm  += __shfl_xor(sm,  off, 64);
  }
  if (lane == 0) { red[0][wid] = se1; red[1][wid] = se2; red[2][wid] = sm; }
  __syncthreads();
  if (tid == 0) {
    atomicAdd(&acc[0], red[0][0] + red[0][1] + red[0][2] + red[0][3]);
    atomicAdd(&acc[1], red[1][0] + red[1][1] + red[1][2] + red[1][3]);
    atomicAdd(&acc[2], red[2][0] + red[2][1] + red[2][2] + red[2][3]);
  }
}

__global__ void loss_kernel(const float* __restrict__ acc, float* __restrict__ out_loss)
{
  if (threadIdx.x == 0 && blockIdx.x == 0) {
    float denom = acc[2] + 1e-12f;
    out_loss[0] = sqrtf(acc[0] / denom) + sqrtf(acc[1] / denom);
  }
}

extern "C" void kernel_launch(void* const* d_in, const int* in_sizes, int n_in,
                              void* d_out, int out_size, void* d_ws, size_t ws_size,
                              hipStream_t stream) {
  const float* Xf    = (const float*)d_in[0];
  const float* Mf    = (const float*)d_in[1];
  const float* Df    = (const float*)d_in[2];
  const float* Xb    = (const float*)d_in[3];
  const float* Mb    = (const float*)d_in[4];
  const float* Db    = (const float*)d_in[5];
  const float* wih_f = (const float*)d_in[6];
  const float* whh_f = (const float*)d_in[7];
  const float* bih_f = (const float*)d_in[8];
  const float* bhh_f = (const float*)d_in[9];
  const float* wih_b = (const float*)d_in[10];
  const float* whh_b = (const float*)d_in[11];
  const float* bih_b = (const float*)d_in[12];
  const float* bhh_b = (const float*)d_in[13];
  const float* Wproj = (const float*)d_in[14];
  const float* bproj = (const float*)d_in[15];
  const float* U     = (const float*)d_in[16];
  const float* V1    = (const float*)d_in[17];
  const float* V2    = (const float*)d_in[18];
  const float* beta  = (const float*)d_in[19];
  const float* Wfin  = (const float*)d_in[20];
  const float* bfin  = (const float*)d_in[21];

  float* est_f = (float*)d_ws;                         // [T, 4096] = 4 MB
  float* est_b = est_f + (size_t)T_ * NROW;            // 4 MB
  float* accp  = est_b + (size_t)T_ * NROW;            // 3 floats

  hipMemsetAsync(accp, 0, 4 * sizeof(float), stream);

  gru_kernel<<<dim3(512), dim3(256), 0, stream>>>(
      Xf, Mf, Df, Xb, Mb, Db,
      wih_f, whh_f, bih_f, bhh_f,
      wih_b, whh_b, bih_b, bhh_b,
      Wproj, est_f, est_b);

  fcn_kernel<<<dim3(256), dim3(256), 0, stream>>>(
      Xf, Mf, U, V1, V2, beta, Wfin, bfin, bproj,
      est_f, est_b, (float*)d_out, accp);

  loss_kernel<<<dim3(1), dim3(64), 0, stream>>>(
      accp, (float*)d_out + (size_t)B_ * T_ * F_);
}

// Round 7
// 294.574 us; speedup vs baseline: 5.2901x; 1.1015x over previous
//
#include <hip/hip_runtime.h>
#include <math.h>

#define B_ 64
#define T_ 256
#define F_ 64
#define H_ 64
#define NROW (B_ * F_) /* 4096 */
#define L2E 1.4426950408889634f

typedef short bf16x8 __attribute__((ext_vector_type(8)));
typedef float f32x4  __attribute__((ext_vector_type(4)));

__device__ __forceinline__ float rcp_f(float x) {
  float r; asm("v_rcp_f32 %0, %1" : "=v"(r) : "v"(x)); return r;
}
__device__ __forceinline__ float exp2_f(float x) {   // 2^x
  float r; asm("v_exp_f32 %0, %1" : "=v"(r) : "v"(x)); return r;
}
__device__ __forceinline__ float exp2n_f(float x) {  // 2^(-x), free neg modifier
  float r; asm("v_exp_f32 %0, -%1" : "=v"(r) : "v"(x)); return r;
}
__device__ __forceinline__ unsigned cvtpk_bf16(float a, float b) { // lo=bf16(a), hi=bf16(b)
  unsigned r; asm("v_cvt_pk_bf16_f32 %0, %1, %2" : "=v"(r) : "v"(a), "v"(b)); return r;
}
__device__ __forceinline__ float bcastf(float v, int k) {
  return __int_as_float(__builtin_amdgcn_readlane(__float_as_int(v), k));
}
__device__ __forceinline__ float tanh_f(float y) {   // plain-argument tanh (fcn uses this)
  return fmaf(-2.0f, rcp_f(1.0f + exp2_f(2.0f * L2E * y)), 1.0f);
}
__device__ __forceinline__ unsigned short bf16_rne(float v) {
  unsigned u = __float_as_uint(v);
  unsigned r = u + 0x7FFFu + ((u >> 16) & 1u);
  return (unsigned short)(r >> 16);
}

#define MFMA16(a, b, c) __builtin_amdgcn_mfma_f32_16x16x32_bf16((a), (b), (c), 0, 0, 0)
// lgkm-only drain (ds writes) + barrier; est global stores need NOT drain here.
#define STEP_BARRIER() asm volatile("s_waitcnt lgkmcnt(0)\n\ts_barrier" ::: "memory")

// WG = 4 waves = 16 rows of one direction; wave w owns units [16w,16w+16).
// Everything matmul-shaped runs on MFMA: h-recurrence (12), input-projection+
// biases via an {x,m,d,1} A-fragment (6), est via W_proj fragment (4, rotating).
// Activations use exp2 with log2e prescaled into the weights.
__global__ void __launch_bounds__(256, 2)
gru_kernel(const float* __restrict__ Xf, const float* __restrict__ Mf, const float* __restrict__ Df,
           const float* __restrict__ Xb, const float* __restrict__ Mb, const float* __restrict__ Db,
           const float* __restrict__ wih_f, const float* __restrict__ whh_f,
           const float* __restrict__ bih_f, const float* __restrict__ bhh_f,
           const float* __restrict__ wih_b, const float* __restrict__ whh_b,
           const float* __restrict__ bih_b, const float* __restrict__ bhh_b,
           const float* __restrict__ Wproj,
           float* __restrict__ est_f, float* __restrict__ est_b)
{
  __shared__ __align__(16) unsigned short s_xa[256][16][8];  // [t][row][k] bf16 {x,m,d,1,0..} 64 KB
  __shared__ unsigned short s_h[2][16][72];                  // [buf][row][unit], pad 72
  __shared__ __align__(16) unsigned short s_zero[8];

  const int tid  = threadIdx.x;
  const int lane = tid & 63;
  const int wid  = tid >> 6;
  const int dir  = blockIdx.x >> 8;
  const int n0   = (blockIdx.x & 255) * 16;
  const int b0   = n0 >> 6;
  const int f0   = n0 & 63;

  const float* X   = dir ? Xb    : Xf;
  const float* M   = dir ? Mb    : Mf;
  const float* D   = dir ? Db    : Df;
  const float* wih = dir ? wih_b : wih_f;
  const float* whh = dir ? whh_b : whh_f;
  const float* bih = dir ? bih_b : bih_f;
  const float* bhh = dir ? bhh_b : bhh_f;
  float* est       = dir ? est_b : est_f;

  const int u     = 16 * wid + (lane & 15);
  const int ucol  = u;
  const int g8    = (lane >> 4) * 8;
  const int arow  = lane & 15;
  const int rbase = (lane >> 4) * 4;

  // gate scales: r,z -> L2E (sigmoid via exp2); n,gin -> 2*L2E (tanh via exp2)
  const float gsc[3] = {L2E, L2E, 2.0f * L2E};

  // ---- h-recurrence B fragments (scaled), hi/lo split ----
  bf16x8 Bhi[3][2], Blo[3][2];
#pragma unroll
  for (int gt = 0; gt < 3; ++gt) {
#pragma unroll
    for (int kh = 0; kh < 2; ++kh) {
      const float* wp = &whh[(gt * 64 + u) * 64 + kh * 32 + g8];
#pragma unroll
      for (int j = 0; j < 8; ++j) {
        float v = wp[j] * gsc[gt];
        unsigned short hb = bf16_rne(v);
        float fhi = __uint_as_float((unsigned)hb << 16);
        Bhi[gt][kh][j] = (short)hb;
        Blo[gt][kh][j] = (short)bf16_rne(v - fhi);
      }
    }
  }

  // ---- xmd B fragments: q=0:r, q=1:z, q=2:gin. k0..2=w_ih*s, k3=bias*s ----
  bf16x8 Bxhi[3], Bxlo[3];
#pragma unroll
  for (int q = 0; q < 3; ++q) {
#pragma unroll
    for (int j = 0; j < 8; ++j) {
      float v = 0.0f;
      if (lane < 16 && j < 4) {
        if (q < 2) v = ((j < 3) ? wih[(q * 64 + u) * 3 + j]
                                : (bih[q * 64 + u] + bhh[q * 64 + u])) * L2E;
        else       v = ((j < 3) ? wih[(2 * 64 + u) * 3 + j]
                                : bih[2 * 64 + u]) * (2.0f * L2E);
      }
      unsigned short hb = bf16_rne(v);
      float fhi = __uint_as_float((unsigned)hb << 16);
      Bxhi[q][j] = (short)hb;
      Bxlo[q][j] = (short)bf16_rne(v - fhi);
    }
  }
  const float bhn2 = bhh[2 * 64 + u] * (2.0f * L2E);   // Cn init (scaled)

  // ---- W_proj B fragments (UNscaled), column 0 only ----
  bf16x8 Bp_hi0, Bp_hi1, Bp_lo0, Bp_lo1;
#pragma unroll
  for (int j = 0; j < 8; ++j) {
    float v0 = ((lane & 15) == 0) ? Wproj[dir * 64 + 0 * 32 + g8 + j] : 0.0f;
    float v1 = ((lane & 15) == 0) ? Wproj[dir * 64 + 1 * 32 + g8 + j] : 0.0f;
    unsigned short h0 = bf16_rne(v0), h1 = bf16_rne(v1);
    float f0h = __uint_as_float((unsigned)h0 << 16);
    float f1h = __uint_as_float((unsigned)h1 << 16);
    Bp_hi0[j] = (short)h0; Bp_hi1[j] = (short)h1;
    Bp_lo0[j] = (short)bf16_rne(v0 - f0h);
    Bp_lo1[j] = (short)bf16_rne(v1 - f1h);
  }

  // ---- preload inputs as bf16 A-fragments ----
  {
    const int f  = tid & 15;
    const int t0 = tid >> 4;
    const size_t rowbase = (size_t)b0 * T_ * F_ + f0 + f;
#pragma unroll 2
    for (int c = 0; c < 16; ++c) {
      int t = t0 + 16 * c;
      size_t gidx = rowbase + (size_t)t * 64;
      float x = X[gidx], m = M[gidx], d = D[gidx];
      int4 w;
      w.x = (int)cvtpk_bf16(x, m);
      w.y = (int)cvtpk_bf16(d, 1.0f);
      w.z = 0; w.w = 0;
      *(int4*)&s_xa[t][f][0] = w;
    }
  }
  for (int i = tid; i < 2 * 16 * 72; i += 256)
    ((unsigned short*)s_h)[i] = 0;
  if (tid < 8) s_zero[tid] = 0;
  __syncthreads();

  f32x4 hold = {0.f, 0.f, 0.f, 0.f};

#pragma unroll 2
  for (int t = 0; t < 256; ++t) {
    const int cur = t & 1, nxt = cur ^ 1;

    bf16x8 Ah0 = *(const bf16x8*)&s_h[cur][arow][g8];
    bf16x8 Ah1 = *(const bf16x8*)&s_h[cur][arow][32 + g8];
    bf16x8 Ax  = *(const bf16x8*)((lane < 16) ? &s_xa[t][arow][0] : &s_zero[0]);

    // est[t-1] from h_{t-1} -- rotating wave, 4 MFMAs, no cross-lane reduce
    if (t > 0 && wid == ((t - 1) & 3)) {
      f32x4 Cp = {0.f, 0.f, 0.f, 0.f};
      Cp = MFMA16(Ah0, Bp_hi0, Cp); Cp = MFMA16(Ah1, Bp_hi1, Cp);
      Cp = MFMA16(Ah0, Bp_lo0, Cp); Cp = MFMA16(Ah1, Bp_lo1, Cp);
      if ((lane & 15) == 0) {
        int tp = t - 1;
        int tt = dir ? (255 - tp) : tp;
        *(f32x4*)&est[(size_t)tt * NROW + n0 + rbase] = Cp;
      }
    }

    f32x4 Cr = {0.f, 0.f, 0.f, 0.f};
    f32x4 Cz = {0.f, 0.f, 0.f, 0.f};
    f32x4 Cg = {0.f, 0.f, 0.f, 0.f};
    f32x4 Cn = {bhn2, bhn2, bhn2, bhn2};

    // input-projection MFMAs (short chains first)
    Cr = MFMA16(Ax, Bxhi[0], Cr); Cr = MFMA16(Ax, Bxlo[0], Cr);
    Cz = MFMA16(Ax, Bxhi[1], Cz); Cz = MFMA16(Ax, Bxlo[1], Cz);
    Cg = MFMA16(Ax, Bxhi[2], Cg); Cg = MFMA16(Ax, Bxlo[2], Cg);
    // h-recurrence MFMAs
    Cr = MFMA16(Ah0, Bhi[0][0], Cr); Cr = MFMA16(Ah1, Bhi[0][1], Cr);
    Cz = MFMA16(Ah0, Bhi[1][0], Cz); Cz = MFMA16(Ah1, Bhi[1][1], Cz);
    Cn = MFMA16(Ah0, Bhi[2][0], Cn); Cn = MFMA16(Ah1, Bhi[2][1], Cn);
    Cr = MFMA16(Ah0, Blo[0][0], Cr); Cr = MFMA16(Ah1, Blo[0][1], Cr);
    Cz = MFMA16(Ah0, Blo[1][0], Cz); Cz = MFMA16(Ah1, Blo[1][1], Cz);
    Cn = MFMA16(Ah0, Blo[2][0], Cn); Cn = MFMA16(Ah1, Blo[2][1], Cn);

#pragma unroll
    for (int r = 0; r < 4; ++r) {
      float rg = rcp_f(1.0f + exp2n_f(Cr[r]));            // sigmoid (prescaled)
      float zg = rcp_f(1.0f + exp2n_f(Cz[r]));
      float yn = fmaf(rg, Cn[r], Cg[r]);                  // 2*log2e * (i_n + r*gh_n)
      float nn = fmaf(-2.0f, rcp_f(1.0f + exp2_f(yn)), 1.0f); // tanh
      float hv = fmaf(zg, hold[r] - nn, nn);              // (1-z)*n + z*h
      hold[r] = hv;
      s_h[nxt][rbase + r][ucol] = (unsigned short)cvtpk_bf16(hv, hv);
    }

    STEP_BARRIER();
  }

  // epilogue: est[255] from final h (buffer 0)
  if (wid == 3) {
    bf16x8 Ah0 = *(const bf16x8*)&s_h[0][arow][g8];
    bf16x8 Ah1 = *(const bf16x8*)&s_h[0][arow][32 + g8];
    f32x4 Cp = {0.f, 0.f, 0.f, 0.f};
    Cp = MFMA16(Ah0, Bp_hi0, Cp); Cp = MFMA16(Ah1, Bp_hi1, Cp);
    Cp = MFMA16(Ah0, Bp_lo0, Cp); Cp = MFMA16(Ah1, Bp_lo1, Cp);
    if ((lane & 15) == 0) {
      int tt = dir ? 0 : 255;
      *(f32x4*)&est[(size_t)tt * NROW + n0 + rbase] = Cp;
    }
  }
}

// FCN via MFMA. WG = 64 samples (4 waves x 16). A = [X | RI | M] (K=192) bf16,
// W1 = [U o m ; V1 o m ; V2] bf16 (diag masked at staging). GEMM1: 24 MFMA/wave;
// tanh; wave-local sH; GEMM2: 8 MFMA/wave. Loss partials in staging/epilogue.
__global__ void __launch_bounds__(256, 2)
fcn_kernel(const float* __restrict__ X, const float* __restrict__ M,
           const float* __restrict__ U, const float* __restrict__ V1, const float* __restrict__ V2,
           const float* __restrict__ beta, const float* __restrict__ Wfin, const float* __restrict__ bfin,
           const float* __restrict__ bproj,
           const float* __restrict__ est_f, const float* __restrict__ est_b,
           float* __restrict__ out, float* __restrict__ acc)
{
  __shared__ unsigned short sA[64][200];
  __shared__ unsigned short sW1[64][200];
  __shared__ unsigned short sW2[64][72];
  __shared__ unsigned short sH[64][72];
  __shared__ float sbeta[64], sbfin[64];
  __shared__ float red[3][4];

  const int tid  = threadIdx.x;
  const int lane = tid & 63;
  const int wid  = tid >> 6;
  const int wg   = blockIdx.x;
  const int bb   = wg >> 2;
  const int t0   = (wg & 3) * 64;

  for (int idx = tid; idx < 4096; idx += 256) {
    int o = idx >> 6, i = idx & 63;
    sW1[o][i]       = bf16_rne((i == o) ? 0.f : U[idx]);
    sW1[o][64 + i]  = bf16_rne((i == o) ? 0.f : V1[idx]);
    sW1[o][128 + i] = bf16_rne(V2[idx]);
    sW2[o][i]       = bf16_rne(Wfin[idx]);
  }
  if (tid < 64) { sbeta[tid] = beta[tid]; sbfin[tid] = bfin[tid]; }

  const float bp = bproj[0];
  float se1 = 0.f, se2 = 0.f, sm = 0.f;
  {
    const int i = lane;
#pragma unroll 1
    for (int p = 0; p < 16; ++p) {
      int s = wid + 4 * p;
      int t = t0 + s;
      size_t gidx = ((size_t)bb * 256 + t) * 64 + i;
      float x = X[gidx], m = M[gidx];
      size_t ei = (size_t)t * NROW + bb * 64 + i;
      float re = est_f[ei] + est_b[ei] + bp;
      float ri = fmaf(m, x - re, re);
      sA[s][i]       = bf16_rne(x);
      sA[s][64 + i]  = bf16_rne(ri);
      sA[s][128 + i] = bf16_rne(m);
      float d2 = (re - x) * m;
      se2 = fmaf(d2, d2, se2); sm += m;
    }
  }
  __syncthreads();

  const int srow0 = wid * 16;
  const int arow  = lane & 15;
  const int g8    = (lane >> 4) * 8;
  const int rb    = srow0 + (lane >> 4) * 4;

  bf16x8 Af[6];
#pragma unroll
  for (int kh = 0; kh < 6; ++kh)
    Af[kh] = *(const bf16x8*)&sA[srow0 + arow][kh * 32 + g8];

  f32x4 Hc[4];
#pragma unroll
  for (int c = 0; c < 4; ++c) {
    float b0 = sbeta[c * 16 + arow];
    f32x4 C = {b0, b0, b0, b0};
#pragma unroll
    for (int kh = 0; kh < 6; ++kh) {
      bf16x8 Bf = *(const bf16x8*)&sW1[c * 16 + arow][kh * 32 + g8];
      C = MFMA16(Af[kh], Bf, C);
    }
    Hc[c] = C;
  }

#pragma unroll
  for (int c = 0; c < 4; ++c)
#pragma unroll
    for (int r = 0; r < 4; ++r)
      sH[rb + r][c * 16 + arow] = bf16_rne(tanh_f(Hc[c][r]));
  __syncthreads();

  bf16x8 A2[2];
#pragma unroll
  for (int kh = 0; kh < 2; ++kh)
    A2[kh] = *(const bf16x8*)&sH[srow0 + arow][kh * 32 + g8];

  f32x4 FE[4];
#pragma unroll
  for (int c = 0; c < 4; ++c) {
    float b0 = sbfin[c * 16 + arow];
    f32x4 C = {b0, b0, b0, b0};
#pragma unroll
    for (int kh = 0; kh < 2; ++kh) {
      bf16x8 B2 = *(const bf16x8*)&sW2[c * 16 + arow][kh * 32 + g8];
      C = MFMA16(A2[kh], B2, C);
    }
    FE[c] = C;
  }

#pragma unroll
  for (int c = 0; c < 4; ++c) {
#pragma unroll
    for (int r = 0; r < 4; ++r) {
      int s = rb + r;
      int o = c * 16 + arow;
      size_t gidx = ((size_t)bb * 256 + (t0 + s)) * 64 + o;
      float x = X[gidx], m = M[gidx];
      float fe = FE[c][r];
      out[gidx] = fmaf(m, x - fe, fe);
      float d1 = (fe - x) * m;
      se1 = fmaf(d1, d1, se1);
    }
  }

#pragma unroll
  for (int off = 32; off; off >>= 1) {
    se1 += __shfl_xor(se1, off, 64);
    se2 += __shfl_xor(se2, off, 64);
    sm  += __shfl_xor(sm,  off, 64);
  }
  if (lane == 0) { red[0][wid] = se1; red[1][wid] = se2; red[2][wid] = sm; }
  __syncthreads();
  if (tid == 0) {
    atomicAdd(&acc[0], red[0][0] + red[0][1] + red[0][2] + red[0][3]);
    atomicAdd(&acc[1], red[1][0] + red[1][1] + red[1][2] + red[1][3]);
    atomicAdd(&acc[2], red[2][0] + red[2][1] + red[2][2] + red[2][3]);
  }
}

__global__ void loss_kernel(const float* __restrict__ acc, float* __restrict__ out_loss)
{
  if (threadIdx.x == 0 && blockIdx.x == 0) {
    float denom = acc[2] + 1e-12f;
    out_loss[0] = sqrtf(acc[0] / denom) + sqrtf(acc[1] / denom);
  }
}

extern "C" void kernel_launch(void* const* d_in, const int* in_sizes, int n_in,
                              void* d_out, int out_size, void* d_ws, size_t ws_size,
                              hipStream_t stream) {
  const float* Xf    = (const float*)d_in[0];
  const float* Mf    = (const float*)d_in[1];
  const float* Df    = (const float*)d_in[2];
  const float* Xb    = (const float*)d_in[3];
  const float* Mb    = (const float*)d_in[4];
  const float* Db    = (const float*)d_in[5];
  const float* wih_f = (const float*)d_in[6];
  const float* whh_f = (const float*)d_in[7];
  const float* bih_f = (const float*)d_in[8];
  const float* bhh_f = (const float*)d_in[9];
  const float* wih_b = (const float*)d_in[10];
  const float* whh_b = (const float*)d_in[11];
  const float* bih_b = (const float*)d_in[12];
  const float* bhh_b = (const float*)d_in[13];
  const float* Wproj = (const float*)d_in[14];
  const float* bproj = (const float*)d_in[15];
  const float* U     = (const float*)d_in[16];
  const float* V1    = (const float*)d_in[17];
  const float* V2    = (const float*)d_in[18];
  const float* beta  = (const float*)d_in[19];
  const float* Wfin  = (const float*)d_in[20];
  const float* bfin  = (const float*)d_in[21];

  float* est_f = (float*)d_ws;
  float* est_b = est_f + (size_t)T_ * NROW;
  float* accp  = est_b + (size_t)T_ * NROW;

  hipMemsetAsync(accp, 0, 4 * sizeof(float), stream);

  gru_kernel<<<dim3(512), dim3(256), 0, stream>>>(
      Xf, Mf, Df, Xb, Mb, Db,
      wih_f, whh_f, bih_f, bhh_f,
      wih_b, whh_b, bih_b, bhh_b,
      Wproj, est_f, est_b);

  fcn_kernel<<<dim3(256), dim3(256), 0, stream>>>(
      Xf, Mf, U, V1, V2, beta, Wfin, bfin, bproj,
      est_f, est_b, (float*)d_out, accp);

  loss_kernel<<<dim3(1), dim3(64), 0, stream>>>(
      accp, (float*)d_out + (size_t)B_ * T_ * F_);
}

// Round 8
// 271.309 us; speedup vs baseline: 5.7437x; 1.0858x over previous
//
#include <hip/hip_runtime.h>
#include <math.h>

#define B_ 64
#define T_ 256
#define F_ 64
#define H_ 64
#define NROW (B_ * F_) /* 4096 */
#define L2E 1.4426950408889634f

typedef short bf16x8 __attribute__((ext_vector_type(8)));
typedef float f32x4  __attribute__((ext_vector_type(4)));

__device__ __forceinline__ float rcp_f(float x) {
  float r; asm("v_rcp_f32 %0, %1" : "=v"(r) : "v"(x)); return r;
}
__device__ __forceinline__ float exp2_f(float x) {   // 2^x
  float r; asm("v_exp_f32 %0, %1" : "=v"(r) : "v"(x)); return r;
}
__device__ __forceinline__ float exp2n_f(float x) {  // 2^(-x), free neg modifier
  float r; asm("v_exp_f32 %0, -%1" : "=v"(r) : "v"(x)); return r;
}
__device__ __forceinline__ unsigned cvtpk_bf16(float a, float b) { // lo=bf16(a), hi=bf16(b)
  unsigned r; asm("v_cvt_pk_bf16_f32 %0, %1, %2" : "=v"(r) : "v"(a), "v"(b)); return r;
}
__device__ __forceinline__ float tanh_f(float y) {   // plain-argument tanh (fcn uses this)
  return fmaf(-2.0f, rcp_f(1.0f + exp2_f(2.0f * L2E * y)), 1.0f);
}
__device__ __forceinline__ unsigned short bf16_rne(float v) {
  unsigned u = __float_as_uint(v);
  unsigned r = u + 0x7FFFu + ((u >> 16) & 1u);
  return (unsigned short)(r >> 16);
}

#define MFMA16(a, b, c) __builtin_amdgcn_mfma_f32_16x16x32_bf16((a), (b), (c), 0, 0, 0)
// lgkm-only drain (ds writes) + barrier; est global stores need NOT drain here.
#define STEP_BARRIER() asm volatile("s_waitcnt lgkmcnt(0)\n\ts_barrier" ::: "memory")

// WG = 4 waves = 16 rows of one direction; wave w owns units [16w,16w+16).
// MFMA everywhere: h-recurrence (hi for r,z; hi+lo for n = 8), input projection
// via {x,m,d,1} A-fragment (6), est via W_proj col-0 fragment (2, rotating wave).
// exp2-activations with log2e prescaled into all weights.
__global__ void __launch_bounds__(256, 2)
gru_kernel(const float* __restrict__ Xf, const float* __restrict__ Mf, const float* __restrict__ Df,
           const float* __restrict__ Xb, const float* __restrict__ Mb, const float* __restrict__ Db,
           const float* __restrict__ wih_f, const float* __restrict__ whh_f,
           const float* __restrict__ bih_f, const float* __restrict__ bhh_f,
           const float* __restrict__ wih_b, const float* __restrict__ whh_b,
           const float* __restrict__ bih_b, const float* __restrict__ bhh_b,
           const float* __restrict__ Wproj,
           float* __restrict__ est_f, float* __restrict__ est_b)
{
  __shared__ __align__(16) unsigned short s_xa[256][16][8];  // [t][row][k] bf16 {x,m,d,1,0..} 64 KB
  __shared__ unsigned short s_h[2][16][72];                  // [buf][row][unit], pad 72
  __shared__ __align__(16) unsigned short s_zero[8];

  const int tid  = threadIdx.x;
  const int lane = tid & 63;
  const int wid  = tid >> 6;
  const int dir  = blockIdx.x >> 8;
  const int n0   = (blockIdx.x & 255) * 16;
  const int b0   = n0 >> 6;
  const int f0   = n0 & 63;

  const float* X   = dir ? Xb    : Xf;
  const float* M   = dir ? Mb    : Mf;
  const float* D   = dir ? Db    : Df;
  const float* wih = dir ? wih_b : wih_f;
  const float* whh = dir ? whh_b : whh_f;
  const float* bih = dir ? bih_b : bih_f;
  const float* bhh = dir ? bhh_b : bhh_f;
  float* est       = dir ? est_b : est_f;

  const int u     = 16 * wid + (lane & 15);
  const int ucol  = u;
  const int g8    = (lane >> 4) * 8;
  const int arow  = lane & 15;
  const int rbase = (lane >> 4) * 4;

  // gate scales: r,z -> L2E (sigmoid via exp2); n,gin -> 2*L2E (tanh via exp2)
  const float gsc[3] = {L2E, L2E, 2.0f * L2E};

  // ---- h-recurrence B fragments: hi for all 3 gates; lo only for n-gate ----
  bf16x8 Bhi[3][2], Blo2[2];
#pragma unroll
  for (int gt = 0; gt < 3; ++gt) {
#pragma unroll
    for (int kh = 0; kh < 2; ++kh) {
      const float* wp = &whh[(gt * 64 + u) * 64 + kh * 32 + g8];
#pragma unroll
      for (int j = 0; j < 8; ++j) {
        float v = wp[j] * gsc[gt];
        unsigned short hb = bf16_rne(v);
        Bhi[gt][kh][j] = (short)hb;
        if (gt == 2) {
          float fhi = __uint_as_float((unsigned)hb << 16);
          Blo2[kh][j] = (short)bf16_rne(v - fhi);
        }
      }
    }
  }

  // ---- xmd B fragments: q=0:r, q=1:z, q=2:gin. k0..2=w_ih*s, k3=bias*s ----
  bf16x8 Bxhi[3], Bxlo[3];
#pragma unroll
  for (int q = 0; q < 3; ++q) {
#pragma unroll
    for (int j = 0; j < 8; ++j) {
      float v = 0.0f;
      if (lane < 16 && j < 4) {
        if (q < 2) v = ((j < 3) ? wih[(q * 64 + u) * 3 + j]
                                : (bih[q * 64 + u] + bhh[q * 64 + u])) * L2E;
        else       v = ((j < 3) ? wih[(2 * 64 + u) * 3 + j]
                                : bih[2 * 64 + u]) * (2.0f * L2E);
      }
      unsigned short hb = bf16_rne(v);
      float fhi = __uint_as_float((unsigned)hb << 16);
      Bxhi[q][j] = (short)hb;
      Bxlo[q][j] = (short)bf16_rne(v - fhi);
    }
  }
  const float bhn2 = bhh[2 * 64 + u] * (2.0f * L2E);   // Cn init (scaled)

  // ---- W_proj B fragment (UNscaled, hi only), column 0 ----
  bf16x8 Bp_hi0, Bp_hi1;
#pragma unroll
  for (int j = 0; j < 8; ++j) {
    float v0 = ((lane & 15) == 0) ? Wproj[dir * 64 + 0 * 32 + g8 + j] : 0.0f;
    float v1 = ((lane & 15) == 0) ? Wproj[dir * 64 + 1 * 32 + g8 + j] : 0.0f;
    Bp_hi0[j] = (short)bf16_rne(v0);
    Bp_hi1[j] = (short)bf16_rne(v1);
  }

  // ---- preload inputs as bf16 A-fragments ----
  {
    const int f  = tid & 15;
    const int t0 = tid >> 4;
    const size_t rowbase = (size_t)b0 * T_ * F_ + f0 + f;
#pragma unroll 2
    for (int c = 0; c < 16; ++c) {
      int t = t0 + 16 * c;
      size_t gidx = rowbase + (size_t)t * 64;
      float x = X[gidx], m = M[gidx], d = D[gidx];
      int4 w;
      w.x = (int)cvtpk_bf16(x, m);
      w.y = (int)cvtpk_bf16(d, 1.0f);
      w.z = 0; w.w = 0;
      *(int4*)&s_xa[t][f][0] = w;
    }
  }
  for (int i = tid; i < 2 * 16 * 72; i += 256)
    ((unsigned short*)s_h)[i] = 0;
  if (tid < 8) s_zero[tid] = 0;
  __syncthreads();

  f32x4 hold = {0.f, 0.f, 0.f, 0.f};

#pragma unroll 2
  for (int t = 0; t < 256; ++t) {
    const int cur = t & 1, nxt = cur ^ 1;

    bf16x8 Ah0 = *(const bf16x8*)&s_h[cur][arow][g8];
    bf16x8 Ah1 = *(const bf16x8*)&s_h[cur][arow][32 + g8];
    bf16x8 Ax  = *(const bf16x8*)((lane < 16) ? &s_xa[t][arow][0] : &s_zero[0]);

    // est[t-1] from h_{t-1} -- rotating wave, 2 MFMAs, no cross-lane reduce
    if (t > 0 && wid == ((t - 1) & 3)) {
      f32x4 Cp = {0.f, 0.f, 0.f, 0.f};
      Cp = MFMA16(Ah0, Bp_hi0, Cp); Cp = MFMA16(Ah1, Bp_hi1, Cp);
      if ((lane & 15) == 0) {
        int tp = t - 1;
        int tt = dir ? (255 - tp) : tp;
        *(f32x4*)&est[(size_t)tt * NROW + n0 + rbase] = Cp;
      }
    }

    f32x4 Cr = {0.f, 0.f, 0.f, 0.f};
    f32x4 Cz = {0.f, 0.f, 0.f, 0.f};
    f32x4 Cg = {0.f, 0.f, 0.f, 0.f};
    f32x4 Cn = {bhn2, bhn2, bhn2, bhn2};

    // input-projection MFMAs (short chains first)
    Cr = MFMA16(Ax, Bxhi[0], Cr); Cr = MFMA16(Ax, Bxlo[0], Cr);
    Cz = MFMA16(Ax, Bxhi[1], Cz); Cz = MFMA16(Ax, Bxlo[1], Cz);
    Cg = MFMA16(Ax, Bxhi[2], Cg); Cg = MFMA16(Ax, Bxlo[2], Cg);
    // h-recurrence MFMAs: hi for r,z; hi+lo for n
    Cr = MFMA16(Ah0, Bhi[0][0], Cr); Cr = MFMA16(Ah1, Bhi[0][1], Cr);
    Cz = MFMA16(Ah0, Bhi[1][0], Cz); Cz = MFMA16(Ah1, Bhi[1][1], Cz);
    Cn = MFMA16(Ah0, Bhi[2][0], Cn); Cn = MFMA16(Ah1, Bhi[2][1], Cn);
    Cn = MFMA16(Ah0, Blo2[0], Cn);   Cn = MFMA16(Ah1, Blo2[1], Cn);

#pragma unroll
    for (int r = 0; r < 4; ++r) {
      float rg = rcp_f(1.0f + exp2n_f(Cr[r]));            // sigmoid (prescaled)
      float zg = rcp_f(1.0f + exp2n_f(Cz[r]));
      float yn = fmaf(rg, Cn[r], Cg[r]);                  // 2*log2e * (i_n + r*gh_n)
      float nn = fmaf(-2.0f, rcp_f(1.0f + exp2_f(yn)), 1.0f); // tanh
      float hv = fmaf(zg, hold[r] - nn, nn);              // (1-z)*n + z*h
      hold[r] = hv;
      s_h[nxt][rbase + r][ucol] = (unsigned short)cvtpk_bf16(hv, hv);
    }

    STEP_BARRIER();
  }

  // epilogue: est[255] from final h (buffer 0)
  if (wid == 3) {
    bf16x8 Ah0 = *(const bf16x8*)&s_h[0][arow][g8];
    bf16x8 Ah1 = *(const bf16x8*)&s_h[0][arow][32 + g8];
    f32x4 Cp = {0.f, 0.f, 0.f, 0.f};
    Cp = MFMA16(Ah0, Bp_hi0, Cp); Cp = MFMA16(Ah1, Bp_hi1, Cp);
    if ((lane & 15) == 0) {
      int tt = dir ? 0 : 255;
      *(f32x4*)&est[(size_t)tt * NROW + n0 + rbase] = Cp;
    }
  }
}

// FCN via MFMA. WG = 64 samples (4 waves x 16). A = [X | RI | M] (K=192) bf16,
// W1 = [U o m ; V1 o m ; V2] bf16 (diag masked at staging). GEMM1: 24 MFMA/wave;
// tanh; wave-local sH; GEMM2: 8 MFMA/wave. Loss partials -> per-WG slot in ws
// (NO atomics: 768 same-address device atomics serialized ~100+ cyc each).
__global__ void __launch_bounds__(256, 2)
fcn_kernel(const float* __restrict__ X, const float* __restrict__ M,
           const float* __restrict__ U, const float* __restrict__ V1, const float* __restrict__ V2,
           const float* __restrict__ beta, const float* __restrict__ Wfin, const float* __restrict__ bfin,
           const float* __restrict__ bproj,
           const float* __restrict__ est_f, const float* __restrict__ est_b,
           float* __restrict__ out, float* __restrict__ part)
{
  __shared__ unsigned short sA[64][200];
  __shared__ unsigned short sW1[64][200];
  __shared__ unsigned short sW2[64][72];
  __shared__ unsigned short sH[64][72];
  __shared__ float sbeta[64], sbfin[64];
  __shared__ float red[3][4];

  const int tid  = threadIdx.x;
  const int lane = tid & 63;
  const int wid  = tid >> 6;
  const int wg   = blockIdx.x;
  const int bb   = wg >> 2;
  const int t0   = (wg & 3) * 64;

  for (int idx = tid; idx < 4096; idx += 256) {
    int o = idx >> 6, i = idx & 63;
    sW1[o][i]       = bf16_rne((i == o) ? 0.f : U[idx]);
    sW1[o][64 + i]  = bf16_rne((i == o) ? 0.f : V1[idx]);
    sW1[o][128 + i] = bf16_rne(V2[idx]);
    sW2[o][i]       = bf16_rne(Wfin[idx]);
  }
  if (tid < 64) { sbeta[tid] = beta[tid]; sbfin[tid] = bfin[tid]; }

  const float bp = bproj[0];
  float se1 = 0.f, se2 = 0.f, sm = 0.f;
  {
    const int i = lane;
#pragma unroll 4
    for (int p = 0; p < 16; ++p) {
      int s = wid + 4 * p;
      int t = t0 + s;
      size_t gidx = ((size_t)bb * 256 + t) * 64 + i;
      float x = X[gidx], m = M[gidx];
      size_t ei = (size_t)t * NROW + bb * 64 + i;
      float re = est_f[ei] + est_b[ei] + bp;
      float ri = fmaf(m, x - re, re);
      sA[s][i]       = bf16_rne(x);
      sA[s][64 + i]  = bf16_rne(ri);
      sA[s][128 + i] = bf16_rne(m);
      float d2 = (re - x) * m;
      se2 = fmaf(d2, d2, se2); sm += m;
    }
  }
  __syncthreads();

  const int srow0 = wid * 16;
  const int arow  = lane & 15;
  const int g8    = (lane >> 4) * 8;
  const int rb    = srow0 + (lane >> 4) * 4;

  bf16x8 Af[6];
#pragma unroll
  for (int kh = 0; kh < 6; ++kh)
    Af[kh] = *(const bf16x8*)&sA[srow0 + arow][kh * 32 + g8];

  f32x4 Hc[4];
#pragma unroll
  for (int c = 0; c < 4; ++c) {
    float b0 = sbeta[c * 16 + arow];
    f32x4 C = {b0, b0, b0, b0};
#pragma unroll
    for (int kh = 0; kh < 6; ++kh) {
      bf16x8 Bf = *(const bf16x8*)&sW1[c * 16 + arow][kh * 32 + g8];
      C = MFMA16(Af[kh], Bf, C);
    }
    Hc[c] = C;
  }

#pragma unroll
  for (int c = 0; c < 4; ++c)
#pragma unroll
    for (int r = 0; r < 4; ++r)
      sH[rb + r][c * 16 + arow] = bf16_rne(tanh_f(Hc[c][r]));
  __syncthreads();

  bf16x8 A2[2];
#pragma unroll
  for (int kh = 0; kh < 2; ++kh)
    A2[kh] = *(const bf16x8*)&sH[srow0 + arow][kh * 32 + g8];

  f32x4 FE[4];
#pragma unroll
  for (int c = 0; c < 4; ++c) {
    float b0 = sbfin[c * 16 + arow];
    f32x4 C = {b0, b0, b0, b0};
#pragma unroll
    for (int kh = 0; kh < 2; ++kh) {
      bf16x8 B2 = *(const bf16x8*)&sW2[c * 16 + arow][kh * 32 + g8];
      C = MFMA16(A2[kh], B2, C);
    }
    FE[c] = C;
  }

#pragma unroll
  for (int c = 0; c < 4; ++c) {
#pragma unroll
    for (int r = 0; r < 4; ++r) {
      int s = rb + r;
      int o = c * 16 + arow;
      size_t gidx = ((size_t)bb * 256 + (t0 + s)) * 64 + o;
      float x = X[gidx], m = M[gidx];
      float fe = FE[c][r];
      out[gidx] = fmaf(m, x - fe, fe);
      float d1 = (fe - x) * m;
      se1 = fmaf(d1, d1, se1);
    }
  }

#pragma unroll
  for (int off = 32; off; off >>= 1) {
    se1 += __shfl_xor(se1, off, 64);
    se2 += __shfl_xor(se2, off, 64);
    sm  += __shfl_xor(sm,  off, 64);
  }
  if (lane == 0) { red[0][wid] = se1; red[1][wid] = se2; red[2][wid] = sm; }
  __syncthreads();
  if (tid == 0) {
    float4 p;
    p.x = red[0][0] + red[0][1] + red[0][2] + red[0][3];
    p.y = red[1][0] + red[1][1] + red[1][2] + red[1][3];
    p.z = red[2][0] + red[2][1] + red[2][2] + red[2][3];
    p.w = 0.f;
    *(float4*)&part[(size_t)wg * 4] = p;     // contention-free partial
  }
}

// Reduce 256 per-WG partials; write final loss scalar.
__global__ void loss_kernel(const float* __restrict__ part, float* __restrict__ out_loss)
{
  __shared__ float red[3][4];
  const int tid = threadIdx.x, lane = tid & 63, wid = tid >> 6;
  float4 p = *(const float4*)&part[(size_t)tid * 4];
  float se1 = p.x, se2 = p.y, sm = p.z;
#pragma unroll
  for (int off = 32; off; off >>= 1) {
    se1 += __shfl_xor(se1, off, 64);
    se2 += __shfl_xor(se2, off, 64);
    sm  += __shfl_xor(sm,  off, 64);
  }
  if (lane == 0) { red[0][wid] = se1; red[1][wid] = se2; red[2][wid] = sm; }
  __syncthreads();
  if (tid == 0) {
    float a0 = red[0][0] + red[0][1] + red[0][2] + red[0][3];
    float a1 = red[1][0] + red[1][1] + red[1][2] + red[1][3];
    float a2 = red[2][0] + red[2][1] + red[2][2] + red[2][3];
    float denom = a2 + 1e-12f;
    out_loss[0] = sqrtf(a1 / denom) + sqrtf(a0 / denom);
  }
}

extern "C" void kernel_launch(void* const* d_in, const int* in_sizes, int n_in,
                              void* d_out, int out_size, void* d_ws, size_t ws_size,
                              hipStream_t stream) {
  const float* Xf    = (const float*)d_in[0];
  const float* Mf    = (const float*)d_in[1];
  const float* Df    = (const float*)d_in[2];
  const float* Xb    = (const float*)d_in[3];
  const float* Mb    = (const float*)d_in[4];
  const float* Db    = (const float*)d_in[5];
  const float* wih_f = (const float*)d_in[6];
  const float* whh_f = (const float*)d_in[7];
  const float* bih_f = (const float*)d_in[8];
  const float* bhh_f = (const float*)d_in[9];
  const float* wih_b = (const float*)d_in[10];
  const float* whh_b = (const float*)d_in[11];
  const float* bih_b = (const float*)d_in[12];
  const float* bhh_b = (const float*)d_in[13];
  const float* Wproj = (const float*)d_in[14];
  const float* bproj = (const float*)d_in[15];
  const float* U     = (const float*)d_in[16];
  const float* V1    = (const float*)d_in[17];
  const float* V2    = (const float*)d_in[18];
  const float* beta  = (const float*)d_in[19];
  const float* Wfin  = (const float*)d_in[20];
  const float* bfin  = (const float*)d_in[21];

  float* est_f = (float*)d_ws;                         // [T, 4096] = 4 MB
  float* est_b = est_f + (size_t)T_ * NROW;            // 4 MB
  float* partp = est_b + (size_t)T_ * NROW;            // 256 x float4 = 4 KB

  gru_kernel<<<dim3(512), dim3(256), 0, stream>>>(
      Xf, Mf, Df, Xb, Mb, Db,
      wih_f, whh_f, bih_f, bhh_f,
      wih_b, whh_b, bih_b, bhh_b,
      Wproj, est_f, est_b);

  fcn_kernel<<<dim3(256), dim3(256), 0, stream>>>(
      Xf, Mf, U, V1, V2, beta, Wfin, bfin, bproj,
      est_f, est_b, (float*)d_out, partp);

  loss_kernel<<<dim3(1), dim3(256), 0, stream>>>(
      partp, (float*)d_out + (size_t)B_ * T_ * F_);
}

// Round 10
// 267.833 us; speedup vs baseline: 5.8182x; 1.0130x over previous
//
#include <hip/hip_runtime.h>
#include <math.h>

#define B_ 64
#define T_ 256
#define F_ 64
#define H_ 64
#define NROW (B_ * F_) /* 4096 */
#define L2E 1.4426950408889634f

typedef short bf16x8 __attribute__((ext_vector_type(8)));
typedef float f32x4  __attribute__((ext_vector_type(4)));

__device__ __forceinline__ float rcp_f(float x) {
  float r; asm("v_rcp_f32 %0, %1" : "=v"(r) : "v"(x)); return r;
}
__device__ __forceinline__ float exp2_f(float x) {   // 2^x
  float r; asm("v_exp_f32 %0, %1" : "=v"(r) : "v"(x)); return r;
}
__device__ __forceinline__ float exp2n_f(float x) {  // 2^(-x), free neg modifier
  float r; asm("v_exp_f32 %0, -%1" : "=v"(r) : "v"(x)); return r;
}
__device__ __forceinline__ unsigned cvtpk_bf16(float a, float b) { // lo=bf16(a), hi=bf16(b)
  unsigned r; asm("v_cvt_pk_bf16_f32 %0, %1, %2" : "=v"(r) : "v"(a), "v"(b)); return r;
}
__device__ __forceinline__ float tanh_f(float y) {   // plain-argument tanh (fcn uses this)
  return fmaf(-2.0f, rcp_f(1.0f + exp2_f(2.0f * L2E * y)), 1.0f);
}
__device__ __forceinline__ unsigned short bf16_rne(float v) {
  unsigned u = __float_as_uint(v);
  unsigned r = u + 0x7FFFu + ((u >> 16) & 1u);
  return (unsigned short)(r >> 16);
}

#define MFMA16(a, b, c) __builtin_amdgcn_mfma_f32_16x16x32_bf16((a), (b), (c), 0, 0, 0)
// lgkm-only drain (ds writes) + barrier; est global stores need NOT drain here.
#define STEP_BARRIER() asm volatile("s_waitcnt lgkmcnt(0)\n\ts_barrier" ::: "memory")

// WG = 4 waves = 16 rows of one direction; wave w owns units [16w,16w+16).
// MFMA everywhere: h-recurrence (hi for r,z; hi+lo for n = 8), input projection
// via {x,m,d,1} A-fragment (6), est via W_proj col-0 fragment (2, rotating wave).
// exp2-activations with log2e prescaled into all weights.  [R8, unchanged]
__global__ void __launch_bounds__(256, 2)
gru_kernel(const float* __restrict__ Xf, const float* __restrict__ Mf, const float* __restrict__ Df,
           const float* __restrict__ Xb, const float* __restrict__ Mb, const float* __restrict__ Db,
           const float* __restrict__ wih_f, const float* __restrict__ whh_f,
           const float* __restrict__ bih_f, const float* __restrict__ bhh_f,
           const float* __restrict__ wih_b, const float* __restrict__ whh_b,
           const float* __restrict__ bih_b, const float* __restrict__ bhh_b,
           const float* __restrict__ Wproj,
           float* __restrict__ est_f, float* __restrict__ est_b)
{
  __shared__ __align__(16) unsigned short s_xa[256][16][8];  // [t][row][k] bf16 {x,m,d,1,0..} 64 KB
  __shared__ unsigned short s_h[2][16][72];                  // [buf][row][unit], pad 72
  __shared__ __align__(16) unsigned short s_zero[8];

  const int tid  = threadIdx.x;
  const int lane = tid & 63;
  const int wid  = tid >> 6;
  const int dir  = blockIdx.x >> 8;
  const int n0   = (blockIdx.x & 255) * 16;
  const int b0   = n0 >> 6;
  const int f0   = n0 & 63;

  const float* X   = dir ? Xb    : Xf;
  const float* M   = dir ? Mb    : Mf;
  const float* D   = dir ? Db    : Df;
  const float* wih = dir ? wih_b : wih_f;
  const float* whh = dir ? whh_b : whh_f;
  const float* bih = dir ? bih_b : bih_f;
  const float* bhh = dir ? bhh_b : bhh_f;
  float* est       = dir ? est_b : est_f;

  const int u     = 16 * wid + (lane & 15);
  const int ucol  = u;
  const int g8    = (lane >> 4) * 8;
  const int arow  = lane & 15;
  const int rbase = (lane >> 4) * 4;

  const float gsc[3] = {L2E, L2E, 2.0f * L2E};

  bf16x8 Bhi[3][2], Blo2[2];
#pragma unroll
  for (int gt = 0; gt < 3; ++gt) {
#pragma unroll
    for (int kh = 0; kh < 2; ++kh) {
      const float* wp = &whh[(gt * 64 + u) * 64 + kh * 32 + g8];
#pragma unroll
      for (int j = 0; j < 8; ++j) {
        float v = wp[j] * gsc[gt];
        unsigned short hb = bf16_rne(v);
        Bhi[gt][kh][j] = (short)hb;
        if (gt == 2) {
          float fhi = __uint_as_float((unsigned)hb << 16);
          Blo2[kh][j] = (short)bf16_rne(v - fhi);
        }
      }
    }
  }

  bf16x8 Bxhi[3], Bxlo[3];
#pragma unroll
  for (int q = 0; q < 3; ++q) {
#pragma unroll
    for (int j = 0; j < 8; ++j) {
      float v = 0.0f;
      if (lane < 16 && j < 4) {
        if (q < 2) v = ((j < 3) ? wih[(q * 64 + u) * 3 + j]
                                : (bih[q * 64 + u] + bhh[q * 64 + u])) * L2E;
        else       v = ((j < 3) ? wih[(2 * 64 + u) * 3 + j]
                                : bih[2 * 64 + u]) * (2.0f * L2E);
      }
      unsigned short hb = bf16_rne(v);
      float fhi = __uint_as_float((unsigned)hb << 16);
      Bxhi[q][j] = (short)hb;
      Bxlo[q][j] = (short)bf16_rne(v - fhi);
    }
  }
  const float bhn2 = bhh[2 * 64 + u] * (2.0f * L2E);

  bf16x8 Bp_hi0, Bp_hi1;
#pragma unroll
  for (int j = 0; j < 8; ++j) {
    float v0 = ((lane & 15) == 0) ? Wproj[dir * 64 + 0 * 32 + g8 + j] : 0.0f;
    float v1 = ((lane & 15) == 0) ? Wproj[dir * 64 + 1 * 32 + g8 + j] : 0.0f;
    Bp_hi0[j] = (short)bf16_rne(v0);
    Bp_hi1[j] = (short)bf16_rne(v1);
  }

  {
    const int f  = tid & 15;
    const int t0 = tid >> 4;
    const size_t rowbase = (size_t)b0 * T_ * F_ + f0 + f;
#pragma unroll 2
    for (int c = 0; c < 16; ++c) {
      int t = t0 + 16 * c;
      size_t gidx = rowbase + (size_t)t * 64;
      float x = X[gidx], m = M[gidx], d = D[gidx];
      int4 w;
      w.x = (int)cvtpk_bf16(x, m);
      w.y = (int)cvtpk_bf16(d, 1.0f);
      w.z = 0; w.w = 0;
      *(int4*)&s_xa[t][f][0] = w;
    }
  }
  for (int i = tid; i < 2 * 16 * 72; i += 256)
    ((unsigned short*)s_h)[i] = 0;
  if (tid < 8) s_zero[tid] = 0;
  __syncthreads();

  f32x4 hold = {0.f, 0.f, 0.f, 0.f};

#pragma unroll 2
  for (int t = 0; t < 256; ++t) {
    const int cur = t & 1, nxt = cur ^ 1;

    bf16x8 Ah0 = *(const bf16x8*)&s_h[cur][arow][g8];
    bf16x8 Ah1 = *(const bf16x8*)&s_h[cur][arow][32 + g8];
    bf16x8 Ax  = *(const bf16x8*)((lane < 16) ? &s_xa[t][arow][0] : &s_zero[0]);

    if (t > 0 && wid == ((t - 1) & 3)) {
      f32x4 Cp = {0.f, 0.f, 0.f, 0.f};
      Cp = MFMA16(Ah0, Bp_hi0, Cp); Cp = MFMA16(Ah1, Bp_hi1, Cp);
      if ((lane & 15) == 0) {
        int tp = t - 1;
        int tt = dir ? (255 - tp) : tp;
        *(f32x4*)&est[(size_t)tt * NROW + n0 + rbase] = Cp;
      }
    }

    f32x4 Cr = {0.f, 0.f, 0.f, 0.f};
    f32x4 Cz = {0.f, 0.f, 0.f, 0.f};
    f32x4 Cg = {0.f, 0.f, 0.f, 0.f};
    f32x4 Cn = {bhn2, bhn2, bhn2, bhn2};

    Cr = MFMA16(Ax, Bxhi[0], Cr); Cr = MFMA16(Ax, Bxlo[0], Cr);
    Cz = MFMA16(Ax, Bxhi[1], Cz); Cz = MFMA16(Ax, Bxlo[1], Cz);
    Cg = MFMA16(Ax, Bxhi[2], Cg); Cg = MFMA16(Ax, Bxlo[2], Cg);
    Cr = MFMA16(Ah0, Bhi[0][0], Cr); Cr = MFMA16(Ah1, Bhi[0][1], Cr);
    Cz = MFMA16(Ah0, Bhi[1][0], Cz); Cz = MFMA16(Ah1, Bhi[1][1], Cz);
    Cn = MFMA16(Ah0, Bhi[2][0], Cn); Cn = MFMA16(Ah1, Bhi[2][1], Cn);
    Cn = MFMA16(Ah0, Blo2[0], Cn);   Cn = MFMA16(Ah1, Blo2[1], Cn);

#pragma unroll
    for (int r = 0; r < 4; ++r) {
      float rg = rcp_f(1.0f + exp2n_f(Cr[r]));
      float zg = rcp_f(1.0f + exp2n_f(Cz[r]));
      float yn = fmaf(rg, Cn[r], Cg[r]);
      float nn = fmaf(-2.0f, rcp_f(1.0f + exp2_f(yn)), 1.0f);
      float hv = fmaf(zg, hold[r] - nn, nn);
      hold[r] = hv;
      s_h[nxt][rbase + r][ucol] = (unsigned short)cvtpk_bf16(hv, hv);
    }

    STEP_BARRIER();
  }

  if (wid == 3) {
    bf16x8 Ah0 = *(const bf16x8*)&s_h[0][arow][g8];
    bf16x8 Ah1 = *(const bf16x8*)&s_h[0][arow][32 + g8];
    f32x4 Cp = {0.f, 0.f, 0.f, 0.f};
    Cp = MFMA16(Ah0, Bp_hi0, Cp); Cp = MFMA16(Ah1, Bp_hi1, Cp);
    if ((lane & 15) == 0) {
      int tt = dir ? 0 : 255;
      *(f32x4*)&est[(size_t)tt * NROW + n0 + rbase] = Cp;
    }
  }
}

// FCN via MFMA. 512 WGs x 32 samples (was 256 x 64): LDS ~53 KB -> 2 blocks/CU
// co-resident (was 1) so global-load latency is TLP-hidden. A = [X|RI|M] K=192
// bf16; W1 = [U∘m;V1∘m;V2]; GEMM1 12 MFMA/wave + tanh; GEMM2 4 MFMA/wave.
// Loss partials -> per-WG slot (no atomics).
__global__ void __launch_bounds__(256, 2)
fcn_kernel(const float* __restrict__ X, const float* __restrict__ M,
           const float* __restrict__ U, const float* __restrict__ V1, const float* __restrict__ V2,
           const float* __restrict__ beta, const float* __restrict__ Wfin, const float* __restrict__ bfin,
           const float* __restrict__ bproj,
           const float* __restrict__ est_f, const float* __restrict__ est_b,
           float* __restrict__ out, float* __restrict__ part)
{
  __shared__ unsigned short sA[32][200];
  __shared__ unsigned short sW1[64][200];
  __shared__ unsigned short sW2[64][72];
  __shared__ unsigned short sH[32][72];
  __shared__ float sbeta[64], sbfin[64];
  __shared__ float red[3][4];

  const int tid  = threadIdx.x;
  const int lane = tid & 63;
  const int wid  = tid >> 6;
  const int wg   = blockIdx.x;              // 0..511
  const int bb   = wg >> 3;                 // batch
  const int t0   = (wg & 7) * 32;           // first timestep

  for (int idx = tid; idx < 4096; idx += 256) {
    int o = idx >> 6, i = idx & 63;
    sW1[o][i]       = bf16_rne((i == o) ? 0.f : U[idx]);
    sW1[o][64 + i]  = bf16_rne((i == o) ? 0.f : V1[idx]);
    sW1[o][128 + i] = bf16_rne(V2[idx]);
    sW2[o][i]       = bf16_rne(Wfin[idx]);
  }
  if (tid < 64) { sbeta[tid] = beta[tid]; sbfin[tid] = bfin[tid]; }

  const float bp = bproj[0];
  float se1 = 0.f, se2 = 0.f, sm = 0.f;
  {
    const int i = lane;
#pragma unroll 4
    for (int p = 0; p < 8; ++p) {
      int s = wid + 4 * p;                  // 0..31
      int t = t0 + s;
      size_t gidx = ((size_t)bb * 256 + t) * 64 + i;
      float x = X[gidx], m = M[gidx];
      size_t ei = (size_t)t * NROW + bb * 64 + i;
      float re = est_f[ei] + est_b[ei] + bp;
      float ri = fmaf(m, x - re, re);
      sA[s][i]       = bf16_rne(x);
      sA[s][64 + i]  = bf16_rne(ri);
      sA[s][128 + i] = bf16_rne(m);
      float d2 = (re - x) * m;
      se2 = fmaf(d2, d2, se2); sm += m;
    }
  }
  __syncthreads();

  const int arow = lane & 15;
  const int g8   = (lane >> 4) * 8;
  const int rb4  = (lane >> 4) * 4;
  const int ocol = wid * 16 + arow;         // wave's output-unit slice

  bf16x8 B1[6], B2f[2];
#pragma unroll
  for (int kh = 0; kh < 6; ++kh) B1[kh]  = *(const bf16x8*)&sW1[ocol][kh * 32 + g8];
#pragma unroll
  for (int kh = 0; kh < 2; ++kh) B2f[kh] = *(const bf16x8*)&sW2[ocol][kh * 32 + g8];
  const float bb1 = sbeta[ocol], bb2 = sbfin[ocol];

#pragma unroll
  for (int tau = 0; tau < 2; ++tau) {       // GEMM1 + tanh
    f32x4 C = {bb1, bb1, bb1, bb1};
#pragma unroll
    for (int kh = 0; kh < 6; ++kh) {
      bf16x8 Af = *(const bf16x8*)&sA[tau * 16 + arow][kh * 32 + g8];
      C = MFMA16(Af, B1[kh], C);
    }
#pragma unroll
    for (int r = 0; r < 4; ++r)
      sH[tau * 16 + rb4 + r][ocol] = bf16_rne(tanh_f(C[r]));
  }
  __syncthreads();

  f32x4 FE[2];
#pragma unroll
  for (int tau = 0; tau < 2; ++tau) {       // GEMM2
    f32x4 C = {bb2, bb2, bb2, bb2};
#pragma unroll
    for (int kh = 0; kh < 2; ++kh) {
      bf16x8 A2 = *(const bf16x8*)&sH[tau * 16 + arow][kh * 32 + g8];
      C = MFMA16(A2, B2f[kh], C);
    }
    FE[tau] = C;
  }

#pragma unroll
  for (int tau = 0; tau < 2; ++tau) {       // epilogue
#pragma unroll
    for (int r = 0; r < 4; ++r) {
      int s = tau * 16 + rb4 + r;
      size_t gidx = ((size_t)bb * 256 + t0 + s) * 64 + ocol;
      float x = X[gidx], m = M[gidx];
      float fe = FE[tau][r];
      out[gidx] = fmaf(m, x - fe, fe);
      float d1 = (fe - x) * m;
      se1 = fmaf(d1, d1, se1);
    }
  }

#pragma unroll
  for (int off = 32; off; off >>= 1) {
    se1 += __shfl_xor(se1, off, 64);
    se2 += __shfl_xor(se2, off, 64);
    sm  += __shfl_xor(sm,  off, 64);
  }
  if (lane == 0) { red[0][wid] = se1; red[1][wid] = se2; red[2][wid] = sm; }
  __syncthreads();
  if (tid == 0) {
    float4 p;
    p.x = red[0][0] + red[0][1] + red[0][2] + red[0][3];
    p.y = red[1][0] + red[1][1] + red[1][2] + red[1][3];
    p.z = red[2][0] + red[2][1] + red[2][2] + red[2][3];
    p.w = 0.f;
    *(float4*)&part[(size_t)wg * 4] = p;    // contention-free partial
  }
}

// Reduce 512 per-WG partials; write final loss scalar.
__global__ void loss_kernel(const float* __restrict__ part, float* __restrict__ out_loss)
{
  __shared__ float red[3][4];
  const int tid = threadIdx.x, lane = tid & 63, wid = tid >> 6;
  float se1 = 0.f, se2 = 0.f, sm = 0.f;
#pragma unroll
  for (int k = tid; k < 512; k += 256) {
    float4 p = *(const float4*)&part[(size_t)k * 4];
    se1 += p.x; se2 += p.y; sm += p.z;
  }
#pragma unroll
  for (int off = 32; off; off >>= 1) {
    se1 += __shfl_xor(se1, off, 64);
    se2 += __shfl_xor(se2, off, 64);
    sm  += __shfl_xor(sm,  off, 64);
  }
  if (lane == 0) { red[0][wid] = se1; red[1][wid] = se2; red[2][wid] = sm; }
  __syncthreads();
  if (tid == 0) {
    float a0 = red[0][0] + red[0][1] + red[0][2] + red[0][3];
    float a1 = red[1][0] + red[1][1] + red[1][2] + red[1][3];
    float a2 = red[2][0] + red[2][1] + red[2][2] + red[2][3];
    float denom = a2 + 1e-12f;
    out_loss[0] = sqrtf(a0 / denom) + sqrtf(a1 / denom);
  }
}

extern "C" void kernel_launch(void* const* d_in, const int* in_sizes, int n_in,
                              void* d_out, int out_size, void* d_ws, size_t ws_size,
                              hipStream_t stream) {
  const float* Xf    = (const float*)d_in[0];
  const float* Mf    = (const float*)d_in[1];
  const float* Df    = (const float*)d_in[2];
  const float* Xb    = (const float*)d_in[3];
  const float* Mb    = (const float*)d_in[4];
  const float* Db    = (const float*)d_in[5];
  const float* wih_f = (const float*)d_in[6];
  const float* whh_f = (const float*)d_in[7];
  const float* bih_f = (const float*)d_in[8];
  const float* bhh_f = (const float*)d_in[9];
  const float* wih_b = (const float*)d_in[10];
  const float* whh_b = (const float*)d_in[11];
  const float* bih_b = (const float*)d_in[12];
  const float* bhh_b = (const float*)d_in[13];
  const float* Wproj = (const float*)d_in[14];
  const float* bproj = (const float*)d_in[15];
  const float* U     = (const float*)d_in[16];
  const float* V1    = (const float*)d_in[17];
  const float* V2    = (const float*)d_in[18];
  const float* beta  = (const float*)d_in[19];
  const float* Wfin  = (const float*)d_in[20];
  const float* bfin  = (const float*)d_in[21];

  float* est_f = (float*)d_ws;                         // [T, 4096] = 4 MB
  float* est_b = est_f + (size_t)T_ * NROW;            // 4 MB
  float* partp = est_b + (size_t)T_ * NROW;            // 512 x float4 = 8 KB

  gru_kernel<<<dim3(512), dim3(256), 0, stream>>>(
      Xf, Mf, Df, Xb, Mb, Db,
      wih_f, whh_f, bih_f, bhh_f,
      wih_b, whh_b, bih_b, bhh_b,
      Wproj, est_f, est_b);

  fcn_kernel<<<dim3(512), dim3(256), 0, stream>>>(
      Xf, Mf, U, V1, V2, beta, Wfin, bfin, bproj,
      est_f, est_b, (float*)d_out, partp);

  loss_kernel<<<dim3(1), dim3(256), 0, stream>>>(
      partp, (float*)d_out + (size_t)B_ * T_ * F_);
}